// Round 2
// baseline (1912.817 us; speedup 1.0000x reference)
//
#include <hip/hip_runtime.h>

#define F_IN 128
#define HID  64
#define NCLS 16

// ---------------- degree / normalization ----------------

__global__ void count_deg(const int* __restrict__ col, float* __restrict__ deg, int E) {
    int e = blockIdx.x * blockDim.x + threadIdx.x;
    if (e < E) atomicAdd(&deg[col[e]], 1.0f);
}

__global__ void make_dinv(float* __restrict__ deg, int N) {
    int i = blockIdx.x * blockDim.x + threadIdx.x;
    if (i < N) deg[i] = rsqrtf(deg[i] + 1.0f);  // +1 = self-loop
}

// ---------------- layer 1 GEMM: hs1 = (x @ W1) * dinv[n]; also init agg1 with self-loop term ----

__global__ __launch_bounds__(256) void gemm1(
    const float* __restrict__ x, const float* __restrict__ W1,
    const float* __restrict__ dinv, float* __restrict__ hs1,
    float* __restrict__ agg1, int N)
{
    __shared__ float Wl[F_IN * HID];   // 32 KB, index k*64+f
    __shared__ float xs[4][F_IN];      // 2 KB
    for (int i = threadIdx.x; i < F_IN * HID; i += 256) Wl[i] = W1[i];
    int node0 = blockIdx.x * 4;
    for (int i = threadIdx.x; i < 4 * F_IN; i += 256) {
        int ln = i >> 7, k = i & 127;
        int n = node0 + ln;
        xs[ln][k] = (n < N) ? x[(size_t)n * F_IN + k] : 0.f;
    }
    __syncthreads();
    int ln = threadIdx.x >> 6;   // wave id = local node
    int f  = threadIdx.x & 63;   // lane = output feature (2-way LDS alias: free)
    int n = node0 + ln;
    if (n < N) {
        float sum = 0.f;
        #pragma unroll 8
        for (int k = 0; k < F_IN; ++k) sum = fmaf(xs[ln][k], Wl[k * HID + f], sum);
        float v = sum * dinv[n];
        size_t o = (size_t)n * HID + f;
        hs1[o]  = v;
        agg1[o] = v;   // self-loop contribution
    }
}

// ---------------- edge scatter, layer 1 (64 feats, 4 per thread) ----------------

__global__ void scatter1(const int* __restrict__ row, const int* __restrict__ col,
                         const float* __restrict__ hs1, float* __restrict__ agg1, int E) {
    long long tid = (long long)blockIdx.x * blockDim.x + threadIdx.x;
    int e = (int)(tid >> 4);
    int g = (int)(tid & 15);
    if (e < E) {
        int r = row[e], c = col[e];
        const float4 v = *(const float4*)(hs1 + (size_t)r * HID + g * 4);
        float* dst = agg1 + (size_t)c * HID + g * 4;
        atomicAdd(dst + 0, v.x);
        atomicAdd(dst + 1, v.y);
        atomicAdd(dst + 2, v.z);
        atomicAdd(dst + 3, v.w);
    }
}

// ---------------- layer-1 epilogue + layer-2 GEMM:
// h2s = dinv[n] * (relu(dinv[n]*agg1[n] + b1) @ W2); also init agg2 with self-loop term ----

__global__ __launch_bounds__(256) void transform(
    const float* __restrict__ agg1, const float* __restrict__ dinv,
    const float* __restrict__ b1, const float* __restrict__ W2,
    float* __restrict__ h2s, float* __restrict__ agg2, int N)
{
    __shared__ float W2l[HID * NCLS];    // 4 KB, index k*16+f
    __shared__ float b1l[HID];
    __shared__ float o1[16][HID + 1];    // +1 pad: phase-2 reads stride 65 -> no bank conflict
    __shared__ float dv[16];
    for (int i = threadIdx.x; i < HID * NCLS; i += 256) W2l[i] = W2[i];
    if (threadIdx.x < HID) b1l[threadIdx.x] = b1[threadIdx.x];
    int node0 = blockIdx.x * 16;
    if (threadIdx.x < 16) {
        int n = node0 + threadIdx.x;
        dv[threadIdx.x] = (n < N) ? dinv[n] : 0.f;
    }
    __syncthreads();
    for (int i = threadIdx.x; i < 16 * HID; i += 256) {
        int ln = i >> 6, f = i & 63;
        int n = node0 + ln;
        float v = 0.f;
        if (n < N) v = fmaxf(fmaf(dv[ln], agg1[(size_t)n * HID + f], b1l[f]), 0.f);
        o1[ln][f] = v;
    }
    __syncthreads();
    int ln = threadIdx.x >> 4;
    int f  = threadIdx.x & 15;
    int n = node0 + ln;
    if (n < N) {
        float sum = 0.f;
        #pragma unroll
        for (int k = 0; k < HID; ++k) sum = fmaf(o1[ln][k], W2l[k * NCLS + f], sum);
        float v = sum * dv[ln];
        size_t o = (size_t)n * NCLS + f;
        h2s[o]  = v;
        agg2[o] = v;   // self-loop contribution
    }
}

// ---------------- edge scatter, layer 2 (16 feats, 4 per thread) ----------------

__global__ void scatter2(const int* __restrict__ row, const int* __restrict__ col,
                         const float* __restrict__ h2s, float* __restrict__ agg2, int E) {
    long long tid = (long long)blockIdx.x * blockDim.x + threadIdx.x;
    int e = (int)(tid >> 2);
    int g = (int)(tid & 3);
    if (e < E) {
        int r = row[e], c = col[e];
        const float4 v = *(const float4*)(h2s + (size_t)r * NCLS + g * 4);
        float* dst = agg2 + (size_t)c * NCLS + g * 4;
        atomicAdd(dst + 0, v.x);
        atomicAdd(dst + 1, v.y);
        atomicAdd(dst + 2, v.z);
        atomicAdd(dst + 3, v.w);
    }
}

// ---------------- final: out = log_softmax(dinv*agg2 + b2), f32 store ----------------

__global__ void finalk(const float* __restrict__ agg2, const float* __restrict__ dinv,
                       const float* __restrict__ b2, float* __restrict__ out, int N) {
    int n = blockIdx.x * blockDim.x + threadIdx.x;
    if (n >= N) return;
    float d = dinv[n];
    float v[NCLS];
    const float4* p = (const float4*)(agg2 + (size_t)n * NCLS);
    #pragma unroll
    for (int i = 0; i < 4; ++i) {
        float4 t = p[i];
        v[4 * i + 0] = t.x; v[4 * i + 1] = t.y; v[4 * i + 2] = t.z; v[4 * i + 3] = t.w;
    }
    float mx = -1e30f;
    #pragma unroll
    for (int i = 0; i < NCLS; ++i) {
        v[i] = fmaf(d, v[i], b2[i]);
        mx = fmaxf(mx, v[i]);
    }
    float s = 0.f;
    #pragma unroll
    for (int i = 0; i < NCLS; ++i) s += expf(v[i] - mx);
    float lse = mx + logf(s);
    float4* dst = (float4*)(out + (size_t)n * NCLS);
    #pragma unroll
    for (int i = 0; i < 4; ++i) {
        float4 t;
        t.x = v[4 * i + 0] - lse; t.y = v[4 * i + 1] - lse;
        t.z = v[4 * i + 2] - lse; t.w = v[4 * i + 3] - lse;
        dst[i] = t;
    }
}

// ---------------- launch ----------------

extern "C" void kernel_launch(void* const* d_in, const int* in_sizes, int n_in,
                              void* d_out, int out_size, void* d_ws, size_t ws_size,
                              hipStream_t stream) {
    const float* x  = (const float*)d_in[0];
    const int*   ei = (const int*)d_in[1];
    const float* W1 = (const float*)d_in[2];
    const float* b1 = (const float*)d_in[3];
    const float* W2 = (const float*)d_in[4];
    const float* b2 = (const float*)d_in[5];
    float* out = (float*)d_out;

    const int N = in_sizes[0] / F_IN;
    const int E = in_sizes[1] / 2;
    const int* row = ei;        // edge_index[0]
    const int* col = ei + E;    // edge_index[1]

    // Workspace layout (aliased to cut footprint to 129*N floats = 51.6 MB):
    //   dinv : ws[0 .. N)
    //   hs1  : bufA (64N)  -- live until scatter1 done
    //   agg1 : bufB (64N)  -- live until transform done
    //   h2s  : bufA[0..16N)    (reuses dead hs1)
    //   agg2 : bufA[16N..32N)
    float* ws   = (float*)d_ws;
    float* dinv = ws;                       // N
    float* bufA = dinv + N;                 // 64N
    float* bufB = bufA + (size_t)N * HID;   // 64N
    float* hs1  = bufA;
    float* agg1 = bufB;
    float* h2s  = bufA;
    float* agg2 = bufA + (size_t)N * NCLS;

    hipMemsetAsync(dinv, 0, (size_t)N * sizeof(float), stream);
    count_deg<<<(E + 255) / 256, 256, 0, stream>>>(col, dinv, E);
    make_dinv<<<(N + 255) / 256, 256, 0, stream>>>(dinv, N);
    gemm1<<<(N + 3) / 4, 256, 0, stream>>>(x, W1, dinv, hs1, agg1, N);
    scatter1<<<(int)(((long long)E * 16 + 255) / 256), 256, 0, stream>>>(row, col, hs1, agg1, E);
    transform<<<(N + 15) / 16, 256, 0, stream>>>(agg1, dinv, b1, W2, h2s, agg2, N);
    scatter2<<<(int)(((long long)E * 4 + 255) / 256), 256, 0, stream>>>(row, col, h2s, agg2, E);
    finalk<<<(N + 255) / 256, 256, 0, stream>>>(agg2, dinv, b2, out, N);
}

// Round 3
// 596.714 us; speedup vs baseline: 3.2056x; 3.2056x over previous
//
#include <hip/hip_runtime.h>

#define F_IN 128
#define HID  64
#define NCLS 16

// ---------------- degree histogram (int) ----------------

__global__ void count_deg(const int* __restrict__ col, int* __restrict__ deg, int E) {
    int e = blockIdx.x * blockDim.x + threadIdx.x;
    if (e < E) atomicAdd(&deg[col[e]], 1);
}

// ---------------- exclusive prefix scan of deg -> row_start (3 kernels) ----------------

__global__ void scan_part(const int* __restrict__ deg, int* __restrict__ row_start,
                          int* __restrict__ bsums, int N) {
    __shared__ int s[256];
    int base = blockIdx.x * 1024 + threadIdx.x * 4;
    int v0 = (base + 0 < N) ? deg[base + 0] : 0;
    int v1 = (base + 1 < N) ? deg[base + 1] : 0;
    int v2 = (base + 2 < N) ? deg[base + 2] : 0;
    int v3 = (base + 3 < N) ? deg[base + 3] : 0;
    int tsum = v0 + v1 + v2 + v3;
    s[threadIdx.x] = tsum;
    __syncthreads();
    for (int off = 1; off < 256; off <<= 1) {
        int t = (threadIdx.x >= off) ? s[threadIdx.x - off] : 0;
        __syncthreads();
        s[threadIdx.x] += t;
        __syncthreads();
    }
    int excl = s[threadIdx.x] - tsum;
    if (base + 0 < N) row_start[base + 0] = excl;
    if (base + 1 < N) row_start[base + 1] = excl + v0;
    if (base + 2 < N) row_start[base + 2] = excl + v0 + v1;
    if (base + 3 < N) row_start[base + 3] = excl + v0 + v1 + v2;
    if (threadIdx.x == 255) bsums[blockIdx.x] = s[255];
}

__global__ void scan_mid(int* __restrict__ bsums, int nb) {
    int run = 0;
    for (int i = 0; i < nb; ++i) { int t = bsums[i]; bsums[i] = run; run += t; }
}

__global__ void scan_fin(const int* __restrict__ deg, int* __restrict__ row_start,
                         const int* __restrict__ bsums, int* __restrict__ cursor,
                         float* __restrict__ dinv, int N, int E) {
    int i = blockIdx.x * blockDim.x + threadIdx.x;
    if (i < N) {
        int rs = row_start[i] + bsums[i >> 10];
        row_start[i] = rs;
        cursor[i] = rs;
        dinv[i] = rsqrtf((float)deg[i] + 1.0f);  // +1 = self-loop
        if (i == N - 1) row_start[N] = E;
    }
}

// ---------------- CSR fill: bucket edges by col (value = row) ----------------

__global__ void fill_csr(const int* __restrict__ row, const int* __restrict__ col,
                         int* __restrict__ cursor, int* __restrict__ csr_row, int E) {
    int e = blockIdx.x * blockDim.x + threadIdx.x;
    if (e < E) {
        int p = atomicAdd(&cursor[col[e]], 1);
        csr_row[p] = row[e];
    }
}

// ---------------- layer 1 GEMM: hs1 = (x @ W1) * dinv[n] ----------------

__global__ __launch_bounds__(256) void gemm1(
    const float* __restrict__ x, const float* __restrict__ W1,
    const float* __restrict__ dinv, float* __restrict__ hs1, int N)
{
    __shared__ float Wl[F_IN * HID];   // 32 KB, index k*64+f
    __shared__ float xs[4][F_IN];      // 2 KB
    for (int i = threadIdx.x; i < (F_IN * HID) / 4; i += 256)
        *(float4*)&Wl[i * 4] = *(const float4*)&W1[i * 4];
    int node0 = blockIdx.x * 4;
    if (threadIdx.x < 128) {
        int ln = threadIdx.x >> 5, k4 = threadIdx.x & 31;
        int n = node0 + ln;
        float4 v = make_float4(0.f, 0.f, 0.f, 0.f);
        if (n < N) v = *(const float4*)&x[(size_t)n * F_IN + k4 * 4];
        *(float4*)&xs[ln][k4 * 4] = v;
    }
    __syncthreads();
    int ln = threadIdx.x >> 6;   // wave id = local node
    int f  = threadIdx.x & 63;   // lane = output feature
    int n = node0 + ln;
    if (n < N) {
        float sum = 0.f;
        #pragma unroll 8
        for (int k = 0; k < F_IN; ++k) sum = fmaf(xs[ln][k], Wl[k * HID + f], sum);
        hs1[(size_t)n * HID + f] = sum * dinv[n];
    }
}

// ---------------- layer-1 gather-aggregate + relu + @W2 (fused) ----------------
// wave per node: lanes = 64 feats; then 64->16 matvec with W2 via LDS.

__global__ __launch_bounds__(256) void agg_l1(
    const float* __restrict__ hs1, const int* __restrict__ rs,
    const int* __restrict__ csr, const float* __restrict__ dinv,
    const float* __restrict__ b1, const float* __restrict__ W2,
    float* __restrict__ h2s, int N)
{
    __shared__ float W2l[HID * NCLS];  // 4 KB
    __shared__ float o1[4][HID];
    for (int i = threadIdx.x; i < HID * NCLS; i += 256) W2l[i] = W2[i];
    int w = threadIdx.x >> 6, f = threadIdx.x & 63;
    int c = blockIdx.x * 4 + w;
    float o = 0.f, dc = 0.f;
    if (c < N) {
        dc = dinv[c];
        float sum = hs1[(size_t)c * HID + f];  // self-loop
        int e0 = rs[c], e1 = rs[c + 1];
        for (int i = e0; i < e1; ++i) {
            int r = csr[i];
            sum += hs1[(size_t)r * HID + f];
        }
        o = fmaxf(fmaf(dc, sum, b1[f]), 0.f);  // relu(dinv*agg + b1)
    }
    o1[w][f] = o;
    __syncthreads();
    if (c < N) {
        int j = f >> 2, part = f & 3;          // 4 lanes per output class-col
        float s16 = 0.f;
        #pragma unroll
        for (int t = 0; t < 16; ++t) {
            int k = part * 16 + t;
            s16 = fmaf(o1[w][k], W2l[k * NCLS + j], s16);
        }
        s16 += __shfl_xor(s16, 1);
        s16 += __shfl_xor(s16, 2);
        if (part == 0) h2s[(size_t)c * NCLS + j] = dc * s16;
    }
}

// ---------------- layer-2 gather-aggregate + log_softmax (fused) ----------------
// thread = (node, class); 16-lane group shares node -> shfl softmax.

__global__ __launch_bounds__(256) void agg2_final(
    const float* __restrict__ h2s, const int* __restrict__ rs,
    const int* __restrict__ csr, const float* __restrict__ dinv,
    const float* __restrict__ b2, float* __restrict__ out, int N)
{
    int tid = blockIdx.x * 256 + threadIdx.x;
    int c = tid >> 4, f = tid & 15;
    if (c >= N) return;
    float sum = h2s[(size_t)c * NCLS + f];     // self-loop
    int e0 = rs[c], e1 = rs[c + 1];
    for (int i = e0; i < e1; ++i) sum += h2s[(size_t)csr[i] * NCLS + f];
    float v = fmaf(dinv[c], sum, b2[f]);
    float mx = v;
    #pragma unroll
    for (int m = 1; m < 16; m <<= 1) mx = fmaxf(mx, __shfl_xor(mx, m, 16));
    float s = __expf(v - mx);
    #pragma unroll
    for (int m = 1; m < 16; m <<= 1) s += __shfl_xor(s, m, 16);
    out[(size_t)c * NCLS + f] = v - mx - __logf(s);
}

// ---------------- launch ----------------

extern "C" void kernel_launch(void* const* d_in, const int* in_sizes, int n_in,
                              void* d_out, int out_size, void* d_ws, size_t ws_size,
                              hipStream_t stream) {
    const float* x  = (const float*)d_in[0];
    const int*   ei = (const int*)d_in[1];
    const float* W1 = (const float*)d_in[2];
    const float* b1 = (const float*)d_in[3];
    const float* W2 = (const float*)d_in[4];
    const float* b2 = (const float*)d_in[5];
    float* out = (float*)d_out;

    const int N = in_sizes[0] / F_IN;
    const int E = in_sizes[1] / 2;
    const int* row = ei;        // edge_index[0] = source
    const int* col = ei + E;    // edge_index[1] = destination

    // Workspace (~40 MB): dinv | hs1 | h2s | deg | row_start | cursor | csr_row | bsums
    size_t Np = ((size_t)N + 3) & ~(size_t)3;
    size_t Ep = ((size_t)E + 3) & ~(size_t)3;
    float* ws   = (float*)d_ws;
    float* dinv = ws;                         // Np
    float* hs1  = dinv + Np;                  // Np*64
    float* h2s  = hs1 + Np * HID;             // Np*16
    int* deg       = (int*)(h2s + Np * NCLS); // Np
    int* row_start = deg + Np;                // Np+4
    int* cursor    = row_start + Np + 4;      // Np
    int* csr_row   = cursor + Np;             // Ep
    int* bsums     = csr_row + Ep;            // nb

    int nb = (N + 1023) / 1024;

    hipMemsetAsync(deg, 0, Np * sizeof(int), stream);
    count_deg<<<(E + 255) / 256, 256, 0, stream>>>(col, deg, E);
    scan_part<<<nb, 256, 0, stream>>>(deg, row_start, bsums, N);
    scan_mid<<<1, 1, 0, stream>>>(bsums, nb);
    scan_fin<<<(N + 255) / 256, 256, 0, stream>>>(deg, row_start, bsums, cursor, dinv, N, E);
    fill_csr<<<(E + 255) / 256, 256, 0, stream>>>(row, col, cursor, csr_row, E);
    gemm1<<<(N + 3) / 4, 256, 0, stream>>>(x, W1, dinv, hs1, N);
    agg_l1<<<(N + 3) / 4, 256, 0, stream>>>(hs1, row_start, csr_row, dinv, b1, W2, h2s, N);
    agg2_final<<<(int)(((size_t)N * 16 + 255) / 256), 256, 0, stream>>>(h2s, row_start, csr_row, dinv, b2, out, N);
}

// Round 4
// 453.871 us; speedup vs baseline: 4.2144x; 1.3147x over previous
//
#include <hip/hip_runtime.h>

#define F_IN 128
#define HID  64
#define NCLS 16

// ---------------- degree histogram (int) ----------------

__global__ void count_deg(const int* __restrict__ col, int* __restrict__ deg, int E) {
    int e = blockIdx.x * blockDim.x + threadIdx.x;
    if (e < E) atomicAdd(&deg[col[e]], 1);
}

// ---------------- exclusive prefix scan of deg -> row_start (3 kernels) ----------------

__global__ void scan_part(const int* __restrict__ deg, int* __restrict__ row_start,
                          int* __restrict__ bsums, int N) {
    __shared__ int s[256];
    int base = blockIdx.x * 1024 + threadIdx.x * 4;
    int v0 = (base + 0 < N) ? deg[base + 0] : 0;
    int v1 = (base + 1 < N) ? deg[base + 1] : 0;
    int v2 = (base + 2 < N) ? deg[base + 2] : 0;
    int v3 = (base + 3 < N) ? deg[base + 3] : 0;
    int tsum = v0 + v1 + v2 + v3;
    s[threadIdx.x] = tsum;
    __syncthreads();
    for (int off = 1; off < 256; off <<= 1) {
        int t = (threadIdx.x >= off) ? s[threadIdx.x - off] : 0;
        __syncthreads();
        s[threadIdx.x] += t;
        __syncthreads();
    }
    int excl = s[threadIdx.x] - tsum;
    if (base + 0 < N) row_start[base + 0] = excl;
    if (base + 1 < N) row_start[base + 1] = excl + v0;
    if (base + 2 < N) row_start[base + 2] = excl + v0 + v1;
    if (base + 3 < N) row_start[base + 3] = excl + v0 + v1 + v2;
    if (threadIdx.x == 255) bsums[blockIdx.x] = s[255];
}

__global__ void scan_mid(int* __restrict__ bsums, int nb) {
    int run = 0;
    for (int i = 0; i < nb; ++i) { int t = bsums[i]; bsums[i] = run; run += t; }
}

__global__ void scan_fin(const int* __restrict__ deg, int* __restrict__ row_start,
                         const int* __restrict__ bsums, int* __restrict__ cursor,
                         float* __restrict__ dinv, int N, int E) {
    int i = blockIdx.x * blockDim.x + threadIdx.x;
    if (i < N) {
        int rs = row_start[i] + bsums[i >> 10];
        row_start[i] = rs;
        cursor[i] = rs;
        dinv[i] = rsqrtf((float)deg[i] + 1.0f);  // +1 = self-loop
        if (i == N - 1) row_start[N] = E;
    }
}

// ---------------- CSR fill: bucket edges by col (value = row) ----------------

__global__ void fill_csr(const int* __restrict__ row, const int* __restrict__ col,
                         int* __restrict__ cursor, int* __restrict__ csr_row, int E) {
    int e = blockIdx.x * blockDim.x + threadIdx.x;
    if (e < E) {
        int p = atomicAdd(&cursor[col[e]], 1);
        csr_row[p] = row[e];
    }
}

// ---------------- layer 1 GEMM: hs1 = (x @ W1) * dinv[n] ----------------
// 32 nodes/block; thread = (wave g, lane f); each thread: 8 nodes x 1 feature,
// register accumulators. W reads: 4x ds_read_b32 conflict-free; x reads:
// wave-uniform ds_read_b128 broadcasts. FMA:LDS = 32:12 per 4-k step.

__global__ __launch_bounds__(256) void gemm1(
    const float* __restrict__ x, const float* __restrict__ W1,
    const float* __restrict__ dinv, float* __restrict__ hs1, int N)
{
    __shared__ float Wl[F_IN * HID];    // 32 KB, index k*64+f
    __shared__ float xs[32 * F_IN];     // 16 KB, 32 node rows
    for (int i = threadIdx.x; i < (F_IN * HID) / 4; i += 256)
        *(float4*)&Wl[i * 4] = *(const float4*)&W1[i * 4];
    size_t gbase = (size_t)blockIdx.x * (32 * F_IN);
    size_t total = (size_t)N * F_IN;
    for (int i = threadIdx.x; i < (32 * F_IN) / 4; i += 256) {
        size_t g = gbase + (size_t)i * 4;
        float4 v = make_float4(0.f, 0.f, 0.f, 0.f);
        if (g < total) v = *(const float4*)&x[g];
        *(float4*)&xs[i * 4] = v;
    }
    __syncthreads();

    int g = threadIdx.x >> 6;   // wave -> node octet
    int f = threadIdx.x & 63;   // lane -> output feature
    float s[8] = {0.f, 0.f, 0.f, 0.f, 0.f, 0.f, 0.f, 0.f};
    #pragma unroll 4
    for (int k = 0; k < F_IN; k += 4) {
        float w0 = Wl[(k + 0) * HID + f];
        float w1 = Wl[(k + 1) * HID + f];
        float w2 = Wl[(k + 2) * HID + f];
        float w3 = Wl[(k + 3) * HID + f];
        #pragma unroll
        for (int u = 0; u < 8; ++u) {
            float4 xv = *(const float4*)&xs[(g * 8 + u) * F_IN + k];
            s[u] = fmaf(xv.x, w0, s[u]);
            s[u] = fmaf(xv.y, w1, s[u]);
            s[u] = fmaf(xv.z, w2, s[u]);
            s[u] = fmaf(xv.w, w3, s[u]);
        }
    }
    int node0 = blockIdx.x * 32 + g * 8;
    #pragma unroll
    for (int u = 0; u < 8; ++u) {
        int n = node0 + u;
        if (n < N) hs1[(size_t)n * HID + f] = s[u] * dinv[n];
    }
}

// ---------------- layer-1 gather-aggregate + relu + @W2 (fused) ----------------
// wave per node, lane = feature; unroll-8 gather for MLP; in-wave shfl matvec
// (no __syncthreads after gather -> waves retire independently).

__global__ __launch_bounds__(256) void agg_l1(
    const float* __restrict__ hs1, const int* __restrict__ rs,
    const int* __restrict__ csr, const float* __restrict__ dinv,
    const float* __restrict__ b1, const float* __restrict__ W2,
    float* __restrict__ h2s, int N)
{
    __shared__ float W2l[HID * NCLS];  // 4 KB
    for (int i = threadIdx.x; i < HID * NCLS; i += 256) W2l[i] = W2[i];
    __syncthreads();
    int w = threadIdx.x >> 6, f = threadIdx.x & 63;
    int c = blockIdx.x * 4 + w;
    if (c >= N) return;
    float dc = dinv[c];
    float sum = hs1[(size_t)c * HID + f];  // self-loop
    int e0 = rs[c], e1 = rs[c + 1];
    int i = e0;
    for (; i + 8 <= e1; i += 8) {
        int r0 = csr[i + 0], r1 = csr[i + 1], r2 = csr[i + 2], r3 = csr[i + 3];
        int r4 = csr[i + 4], r5 = csr[i + 5], r6 = csr[i + 6], r7 = csr[i + 7];
        float a0 = hs1[(size_t)r0 * HID + f];
        float a1 = hs1[(size_t)r1 * HID + f];
        float a2 = hs1[(size_t)r2 * HID + f];
        float a3 = hs1[(size_t)r3 * HID + f];
        float a4 = hs1[(size_t)r4 * HID + f];
        float a5 = hs1[(size_t)r5 * HID + f];
        float a6 = hs1[(size_t)r6 * HID + f];
        float a7 = hs1[(size_t)r7 * HID + f];
        sum += ((a0 + a1) + (a2 + a3)) + ((a4 + a5) + (a6 + a7));
    }
    for (; i < e1; ++i) sum += hs1[(size_t)csr[i] * HID + f];
    float o = fmaxf(fmaf(dc, sum, b1[f]), 0.f);   // relu(dinv*agg + b1)

    // 64 -> 16 matvec with W2, split 4 ways along k, in-wave via shfl
    int j = f >> 2, part = f & 3;
    float s16 = 0.f;
    #pragma unroll
    for (int t = 0; t < 16; ++t) {
        int k = part * 16 + t;
        float ok = __shfl(o, k, 64);
        s16 = fmaf(ok, W2l[k * NCLS + j], s16);
    }
    s16 += __shfl_xor(s16, 1);
    s16 += __shfl_xor(s16, 2);
    if (part == 0) h2s[(size_t)c * NCLS + j] = dc * s16;
}

// ---------------- layer-2 gather-aggregate + log_softmax (fused) ----------------
// thread = (node, class); unroll-4 gather; 16-lane shfl softmax.

__global__ __launch_bounds__(256) void agg2_final(
    const float* __restrict__ h2s, const int* __restrict__ rs,
    const int* __restrict__ csr, const float* __restrict__ dinv,
    const float* __restrict__ b2, float* __restrict__ out, int N)
{
    int tid = blockIdx.x * 256 + threadIdx.x;
    int c = tid >> 4, f = tid & 15;
    if (c >= N) return;
    float sum = h2s[(size_t)c * NCLS + f];     // self-loop
    int e0 = rs[c], e1 = rs[c + 1];
    int i = e0;
    for (; i + 4 <= e1; i += 4) {
        int r0 = csr[i + 0], r1 = csr[i + 1], r2 = csr[i + 2], r3 = csr[i + 3];
        float a0 = h2s[(size_t)r0 * NCLS + f];
        float a1 = h2s[(size_t)r1 * NCLS + f];
        float a2 = h2s[(size_t)r2 * NCLS + f];
        float a3 = h2s[(size_t)r3 * NCLS + f];
        sum += (a0 + a1) + (a2 + a3);
    }
    for (; i < e1; ++i) sum += h2s[(size_t)csr[i] * NCLS + f];
    float v = fmaf(dinv[c], sum, b2[f]);
    float mx = v;
    #pragma unroll
    for (int m = 1; m < 16; m <<= 1) mx = fmaxf(mx, __shfl_xor(mx, m, 16));
    float s = __expf(v - mx);
    #pragma unroll
    for (int m = 1; m < 16; m <<= 1) s += __shfl_xor(s, m, 16);
    out[(size_t)c * NCLS + f] = v - mx - __logf(s);
}

// ---------------- launch ----------------

extern "C" void kernel_launch(void* const* d_in, const int* in_sizes, int n_in,
                              void* d_out, int out_size, void* d_ws, size_t ws_size,
                              hipStream_t stream) {
    const float* x  = (const float*)d_in[0];
    const int*   ei = (const int*)d_in[1];
    const float* W1 = (const float*)d_in[2];
    const float* b1 = (const float*)d_in[3];
    const float* W2 = (const float*)d_in[4];
    const float* b2 = (const float*)d_in[5];
    float* out = (float*)d_out;

    const int N = in_sizes[0] / F_IN;
    const int E = in_sizes[1] / 2;
    const int* row = ei;        // edge_index[0] = source
    const int* col = ei + E;    // edge_index[1] = destination

    size_t Np = ((size_t)N + 3) & ~(size_t)3;
    size_t Ep = ((size_t)E + 3) & ~(size_t)3;
    float* ws   = (float*)d_ws;
    float* dinv = ws;                         // Np
    float* hs1  = dinv + Np;                  // Np*64
    float* h2s  = hs1 + Np * HID;             // Np*16
    int* deg       = (int*)(h2s + Np * NCLS); // Np
    int* row_start = deg + Np;                // Np+4
    int* cursor    = row_start + Np + 4;      // Np
    int* csr_row   = cursor + Np;             // Ep
    int* bsums     = csr_row + Ep;            // nb

    int nb = (N + 1023) / 1024;

    hipMemsetAsync(deg, 0, Np * sizeof(int), stream);
    count_deg<<<(E + 255) / 256, 256, 0, stream>>>(col, deg, E);
    scan_part<<<nb, 256, 0, stream>>>(deg, row_start, bsums, N);
    scan_mid<<<1, 1, 0, stream>>>(bsums, nb);
    scan_fin<<<(N + 255) / 256, 256, 0, stream>>>(deg, row_start, bsums, cursor, dinv, N, E);
    fill_csr<<<(E + 255) / 256, 256, 0, stream>>>(row, col, cursor, csr_row, E);
    gemm1<<<(N + 31) / 32, 256, 0, stream>>>(x, W1, dinv, hs1, N);
    agg_l1<<<(N + 3) / 4, 256, 0, stream>>>(hs1, row_start, csr_row, dinv, b1, W2, h2s, N);
    agg2_final<<<(int)(((size_t)N * 16 + 255) / 256), 256, 0, stream>>>(h2s, row_start, csr_row, dinv, b2, out, N);
}

// Round 5
// 311.819 us; speedup vs baseline: 6.1344x; 1.4556x over previous
//
#include <hip/hip_runtime.h>
#include <hip/hip_fp16.h>

#define F_IN 128
#define HID  64
#define NCLS 16
#define NPB  128      // nodes per bucket (pow2); bucket = col >> 7
#define CHUNK 8192    // edges per bucket_hist/phaseA block

// ---------------- bucket histogram (LDS, then fire-and-forget global add) ----------------

__global__ __launch_bounds__(256) void bucket_hist(const int* __restrict__ col,
                                                   int* __restrict__ tot, int E, int NB) {
    __shared__ int hist[1024];                    // NB <= 1024 (N <= 131072)
    for (int i = threadIdx.x; i < NB; i += 256) hist[i] = 0;
    __syncthreads();
    int e0 = blockIdx.x * CHUNK;
    #pragma unroll 4
    for (int j = 0; j < CHUNK / 256; ++j) {
        int e = e0 + j * 256 + threadIdx.x;
        if (e < E) atomicAdd(&hist[col[e] >> 7], 1);
    }
    __syncthreads();
    for (int i = threadIdx.x; i < NB; i += 256)
        if (hist[i]) atomicAdd(&tot[i], hist[i]);
}

// ---------------- one-block parallel exclusive scan of bucket totals ----------------

__global__ __launch_bounds__(256) void bucket_scan(const int* __restrict__ tot,
                                                   int* __restrict__ base, int* __restrict__ cursor,
                                                   int* __restrict__ row_start, int NB, int N, int E) {
    __shared__ int s[256];
    int t = threadIdx.x, i0 = t * 4;
    int v0 = (i0 + 0 < NB) ? tot[i0 + 0] : 0;
    int v1 = (i0 + 1 < NB) ? tot[i0 + 1] : 0;
    int v2 = (i0 + 2 < NB) ? tot[i0 + 2] : 0;
    int v3 = (i0 + 3 < NB) ? tot[i0 + 3] : 0;
    int tsum = v0 + v1 + v2 + v3;
    s[t] = tsum;
    __syncthreads();
    for (int off = 1; off < 256; off <<= 1) {
        int x = (t >= off) ? s[t - off] : 0;
        __syncthreads();
        s[t] += x;
        __syncthreads();
    }
    int run = s[t] - tsum;
    if (i0 + 0 < NB) { base[i0 + 0] = run; cursor[i0 + 0] = run; } run += v0;
    if (i0 + 1 < NB) { base[i0 + 1] = run; cursor[i0 + 1] = run; } run += v1;
    if (i0 + 2 < NB) { base[i0 + 2] = run; cursor[i0 + 2] = run; } run += v2;
    if (i0 + 3 < NB) { base[i0 + 3] = run; cursor[i0 + 3] = run; }
    if (t == 0) { base[NB] = E; row_start[N] = E; }
}

// ---------------- phase A: bin edges by bucket into int2 (row,col) regions ----------------
// Global returning-atomics: one per (block,bucket) = ~153k (vs 1.6M before).
// Writes are ~10-edge contiguous runs -> ~1x cacheline amplification.

__global__ __launch_bounds__(256) void phaseA(const int* __restrict__ row, const int* __restrict__ col,
                                              int* __restrict__ cursor, int2* __restrict__ ebuf,
                                              int E, int NB) {
    __shared__ int hist[1024], base[1024], off[1024];
    for (int i = threadIdx.x; i < NB; i += 256) hist[i] = 0;
    __syncthreads();
    int e0 = blockIdx.x * CHUNK;
    #pragma unroll 4
    for (int j = 0; j < CHUNK / 256; ++j) {
        int e = e0 + j * 256 + threadIdx.x;
        if (e < E) atomicAdd(&hist[col[e] >> 7], 1);
    }
    __syncthreads();
    for (int i = threadIdx.x; i < NB; i += 256) {
        int h = hist[i];
        base[i] = h ? atomicAdd(&cursor[i], h) : 0;
        off[i] = 0;
    }
    __syncthreads();
    #pragma unroll 4
    for (int j = 0; j < CHUNK / 256; ++j) {
        int e = e0 + j * 256 + threadIdx.x;
        if (e < E) {
            int c = col[e], b = c >> 7;
            int p = base[b] + atomicAdd(&off[b], 1);
            ebuf[p] = make_int2(row[e], c);
        }
    }
}

// ---------------- phase B: per-bucket CSR finalize, all cursors in LDS ----------------
// Also produces per-node row_start, deg->dinv (replaces count_deg + global scan).

__global__ __launch_bounds__(256) void phaseB(const int2* __restrict__ ebuf, const int* __restrict__ bbase,
                                              int* __restrict__ row_start, int* __restrict__ csr_row,
                                              float* __restrict__ dinv, int N) {
    __shared__ int hist[NPB], sc[NPB], cur[NPB];
    int t = threadIdx.x;
    int node0 = blockIdx.x << 7;
    int e0 = bbase[blockIdx.x], e1 = bbase[blockIdx.x + 1];
    if (t < NPB) hist[t] = 0;
    __syncthreads();
    for (int e = e0 + t; e < e1; e += 256) atomicAdd(&hist[ebuf[e].y & (NPB - 1)], 1);
    __syncthreads();
    if (t < NPB) sc[t] = hist[t];
    __syncthreads();
    for (int off = 1; off < NPB; off <<= 1) {
        int x = (t < NPB && t >= off) ? sc[t - off] : 0;
        __syncthreads();
        if (t < NPB) sc[t] += x;
        __syncthreads();
    }
    if (t < NPB) {
        int start = e0 + sc[t] - hist[t];     // exclusive
        cur[t] = start;
        int n = node0 + t;
        if (n < N) {
            row_start[n] = start;
            dinv[n] = rsqrtf((float)hist[t] + 1.0f);  // +1 = self-loop
        }
    }
    __syncthreads();
    for (int e = e0 + t; e < e1; e += 256) {
        int2 p = ebuf[e];
        int pos = atomicAdd(&cur[p.y & (NPB - 1)], 1);
        csr_row[pos] = p.x;                   // write stays within a ~6KB L2-local region
    }
}

// ---------------- layer 1 GEMM: hs1 = fp16((x @ W1) * dinv[n]) ----------------

__global__ __launch_bounds__(256) void gemm1(
    const float* __restrict__ x, const float* __restrict__ W1,
    const float* __restrict__ dinv, __half* __restrict__ hs1, int N)
{
    __shared__ float Wl[F_IN * HID];    // 32 KB
    __shared__ float xs[32 * F_IN];     // 16 KB
    for (int i = threadIdx.x; i < (F_IN * HID) / 4; i += 256)
        *(float4*)&Wl[i * 4] = *(const float4*)&W1[i * 4];
    size_t gbase = (size_t)blockIdx.x * (32 * F_IN);
    size_t total = (size_t)N * F_IN;
    for (int i = threadIdx.x; i < (32 * F_IN) / 4; i += 256) {
        size_t g = gbase + (size_t)i * 4;
        float4 v = make_float4(0.f, 0.f, 0.f, 0.f);
        if (g < total) v = *(const float4*)&x[g];
        *(float4*)&xs[i * 4] = v;
    }
    __syncthreads();
    int g = threadIdx.x >> 6;
    int f = threadIdx.x & 63;
    float s[8] = {0.f, 0.f, 0.f, 0.f, 0.f, 0.f, 0.f, 0.f};
    #pragma unroll 4
    for (int k = 0; k < F_IN; k += 4) {
        float w0 = Wl[(k + 0) * HID + f];
        float w1 = Wl[(k + 1) * HID + f];
        float w2 = Wl[(k + 2) * HID + f];
        float w3 = Wl[(k + 3) * HID + f];
        #pragma unroll
        for (int u = 0; u < 8; ++u) {
            float4 xv = *(const float4*)&xs[(g * 8 + u) * F_IN + k];
            s[u] = fmaf(xv.x, w0, s[u]);
            s[u] = fmaf(xv.y, w1, s[u]);
            s[u] = fmaf(xv.z, w2, s[u]);
            s[u] = fmaf(xv.w, w3, s[u]);
        }
    }
    int node0 = blockIdx.x * 32 + g * 8;
    #pragma unroll
    for (int u = 0; u < 8; ++u) {
        int n = node0 + u;
        if (n < N) hs1[(size_t)n * HID + f] = __float2half(s[u] * dinv[n]);
    }
}

// ---------------- layer-1 gather-aggregate (fp16) + relu + @W2 (fused) ----------------

__global__ __launch_bounds__(256) void agg_l1(
    const __half* __restrict__ hs1, const int* __restrict__ rs,
    const int* __restrict__ csr, const float* __restrict__ dinv,
    const float* __restrict__ b1, const float* __restrict__ W2,
    __half* __restrict__ h2s, int N)
{
    __shared__ float W2l[HID * NCLS];  // 4 KB
    for (int i = threadIdx.x; i < HID * NCLS; i += 256) W2l[i] = W2[i];
    __syncthreads();
    int w = threadIdx.x >> 6, f = threadIdx.x & 63;
    int c = blockIdx.x * 4 + w;
    if (c >= N) return;
    float dc = dinv[c];
    float sum = __half2float(hs1[(size_t)c * HID + f]);  // self-loop
    int e0 = rs[c], e1 = rs[c + 1];
    int i = e0;
    for (; i + 8 <= e1; i += 8) {
        int r0 = csr[i + 0], r1 = csr[i + 1], r2 = csr[i + 2], r3 = csr[i + 3];
        int r4 = csr[i + 4], r5 = csr[i + 5], r6 = csr[i + 6], r7 = csr[i + 7];
        float a0 = __half2float(hs1[(size_t)r0 * HID + f]);
        float a1 = __half2float(hs1[(size_t)r1 * HID + f]);
        float a2 = __half2float(hs1[(size_t)r2 * HID + f]);
        float a3 = __half2float(hs1[(size_t)r3 * HID + f]);
        float a4 = __half2float(hs1[(size_t)r4 * HID + f]);
        float a5 = __half2float(hs1[(size_t)r5 * HID + f]);
        float a6 = __half2float(hs1[(size_t)r6 * HID + f]);
        float a7 = __half2float(hs1[(size_t)r7 * HID + f]);
        sum += ((a0 + a1) + (a2 + a3)) + ((a4 + a5) + (a6 + a7));
    }
    for (; i < e1; ++i) sum += __half2float(hs1[(size_t)csr[i] * HID + f]);
    float o = fmaxf(fmaf(dc, sum, b1[f]), 0.f);

    // 64 -> 16 matvec with W2, split 4 ways along k, in-wave via shfl
    int j = f >> 2, part = f & 3;
    float s16 = 0.f;
    #pragma unroll
    for (int t = 0; t < 16; ++t) {
        int k = part * 16 + t;
        float ok = __shfl(o, k, 64);
        s16 = fmaf(ok, W2l[k * NCLS + j], s16);
    }
    s16 += __shfl_xor(s16, 1);
    s16 += __shfl_xor(s16, 2);
    if (part == 0) h2s[(size_t)c * NCLS + j] = __float2half(dc * s16);
}

// ---------------- layer-2 gather-aggregate (fp16) + log_softmax (fused) ----------------

__global__ __launch_bounds__(256) void agg2_final(
    const __half* __restrict__ h2s, const int* __restrict__ rs,
    const int* __restrict__ csr, const float* __restrict__ dinv,
    const float* __restrict__ b2, float* __restrict__ out, int N)
{
    int tid = blockIdx.x * 256 + threadIdx.x;
    int c = tid >> 4, f = tid & 15;
    if (c >= N) return;
    float sum = __half2float(h2s[(size_t)c * NCLS + f]);  // self-loop
    int e0 = rs[c], e1 = rs[c + 1];
    int i = e0;
    for (; i + 4 <= e1; i += 4) {
        int r0 = csr[i + 0], r1 = csr[i + 1], r2 = csr[i + 2], r3 = csr[i + 3];
        float a0 = __half2float(h2s[(size_t)r0 * NCLS + f]);
        float a1 = __half2float(h2s[(size_t)r1 * NCLS + f]);
        float a2 = __half2float(h2s[(size_t)r2 * NCLS + f]);
        float a3 = __half2float(h2s[(size_t)r3 * NCLS + f]);
        sum += (a0 + a1) + (a2 + a3);
    }
    for (; i < e1; ++i) sum += __half2float(h2s[(size_t)csr[i] * NCLS + f]);
    float v = fmaf(dinv[c], sum, b2[f]);
    float mx = v;
    #pragma unroll
    for (int m = 1; m < 16; m <<= 1) mx = fmaxf(mx, __shfl_xor(mx, m, 16));
    float s = __expf(v - mx);
    #pragma unroll
    for (int m = 1; m < 16; m <<= 1) s += __shfl_xor(s, m, 16);
    out[(size_t)c * NCLS + f] = v - mx - __logf(s);
}

// ---------------- launch ----------------

extern "C" void kernel_launch(void* const* d_in, const int* in_sizes, int n_in,
                              void* d_out, int out_size, void* d_ws, size_t ws_size,
                              hipStream_t stream) {
    const float* x  = (const float*)d_in[0];
    const int*   ei = (const int*)d_in[1];
    const float* W1 = (const float*)d_in[2];
    const float* b1 = (const float*)d_in[3];
    const float* W2 = (const float*)d_in[4];
    const float* b2 = (const float*)d_in[5];
    float* out = (float*)d_out;

    const int N = in_sizes[0] / F_IN;
    const int E = in_sizes[1] / 2;
    const int* row = ei;        // edge_index[0] = source
    const int* col = ei + E;    // edge_index[1] = destination

    const int NB = (N + NPB - 1) / NPB;          // buckets (782 for N=100k); must be <= 1024
    size_t Np  = ((size_t)N + 15) & ~(size_t)15;
    size_t Ep  = ((size_t)E + 15) & ~(size_t)15;
    size_t NBp = ((size_t)NB + 15) & ~(size_t)15;

    // Workspace (~36 MB), all segments 16B-aligned:
    char* p = (char*)d_ws;
    float*  dinv      = (float*)p;   p += Np * 4;
    __half* hs1       = (__half*)p;  p += Np * HID * 2;
    __half* h2s       = (__half*)p;  p += Np * NCLS * 2;
    int*    row_start = (int*)p;     p += (Np + 16) * 4;
    int*    csr_row   = (int*)p;     p += Ep * 4;
    int2*   ebuf      = (int2*)p;    p += Ep * 8;
    int*    btot      = (int*)p;     p += NBp * 4;
    int*    bbase     = (int*)p;     p += (NBp + 16) * 4;
    int*    bcur      = (int*)p;     p += NBp * 4;

    int nblkE = (E + CHUNK - 1) / CHUNK;

    hipMemsetAsync(btot, 0, NBp * sizeof(int), stream);
    bucket_hist<<<nblkE, 256, 0, stream>>>(col, btot, E, NB);
    bucket_scan<<<1, 256, 0, stream>>>(btot, bbase, bcur, row_start, NB, N, E);
    phaseA<<<nblkE, 256, 0, stream>>>(row, col, bcur, ebuf, E, NB);
    phaseB<<<NB, 256, 0, stream>>>(ebuf, bbase, row_start, csr_row, dinv, N);
    gemm1<<<(N + 31) / 32, 256, 0, stream>>>(x, W1, dinv, hs1, N);
    agg_l1<<<(N + 3) / 4, 256, 0, stream>>>(hs1, row_start, csr_row, dinv, b1, W2, h2s, N);
    agg2_final<<<(int)(((size_t)N * 16 + 255) / 256), 256, 0, stream>>>(h2s, row_start, csr_row, dinv, b2, out, N);
}

// Round 6
// 283.276 us; speedup vs baseline: 6.7525x; 1.1008x over previous
//
#include <hip/hip_runtime.h>
#include <hip/hip_fp16.h>

#define F_IN 128
#define HID  64
#define NCLS 16
#define NPB  128      // nodes per bucket (pow2); bucket = col >> 7
#define CHUNK 8192    // edges per bucket_hist/phaseA block
#define GPAD 136      // padded A-row stride (halfs) for gemm1 LDS

typedef _Float16 half_t;
typedef __attribute__((ext_vector_type(8))) _Float16 half8;
typedef __attribute__((ext_vector_type(4))) float float4v;

// ---------------- bucket histogram (LDS, then fire-and-forget global add) ----------------

__global__ __launch_bounds__(256) void bucket_hist(const int* __restrict__ col,
                                                   int* __restrict__ tot, int E, int NB) {
    __shared__ int hist[1024];                    // NB <= 1024 (N <= 131072)
    for (int i = threadIdx.x; i < NB; i += 256) hist[i] = 0;
    __syncthreads();
    int e0 = blockIdx.x * CHUNK;
    #pragma unroll 4
    for (int j = 0; j < CHUNK / 256; ++j) {
        int e = e0 + j * 256 + threadIdx.x;
        if (e < E) atomicAdd(&hist[col[e] >> 7], 1);
    }
    __syncthreads();
    for (int i = threadIdx.x; i < NB; i += 256)
        if (hist[i]) atomicAdd(&tot[i], hist[i]);
}

// ---------------- one-block parallel exclusive scan of bucket totals ----------------

__global__ __launch_bounds__(256) void bucket_scan(const int* __restrict__ tot,
                                                   int* __restrict__ base, int* __restrict__ cursor,
                                                   int* __restrict__ row_start, int NB, int N, int E) {
    __shared__ int s[256];
    int t = threadIdx.x, i0 = t * 4;
    int v0 = (i0 + 0 < NB) ? tot[i0 + 0] : 0;
    int v1 = (i0 + 1 < NB) ? tot[i0 + 1] : 0;
    int v2 = (i0 + 2 < NB) ? tot[i0 + 2] : 0;
    int v3 = (i0 + 3 < NB) ? tot[i0 + 3] : 0;
    int tsum = v0 + v1 + v2 + v3;
    s[t] = tsum;
    __syncthreads();
    for (int off = 1; off < 256; off <<= 1) {
        int x = (t >= off) ? s[t - off] : 0;
        __syncthreads();
        s[t] += x;
        __syncthreads();
    }
    int run = s[t] - tsum;
    if (i0 + 0 < NB) { base[i0 + 0] = run; cursor[i0 + 0] = run; } run += v0;
    if (i0 + 1 < NB) { base[i0 + 1] = run; cursor[i0 + 1] = run; } run += v1;
    if (i0 + 2 < NB) { base[i0 + 2] = run; cursor[i0 + 2] = run; } run += v2;
    if (i0 + 3 < NB) { base[i0 + 3] = run; cursor[i0 + 3] = run; }
    if (t == 0) { base[NB] = E; row_start[N] = E; }
}

// ---------------- phase A: bin edges by bucket into int2 (row,col) regions ----------------

__global__ __launch_bounds__(256) void phaseA(const int* __restrict__ row, const int* __restrict__ col,
                                              int* __restrict__ cursor, int2* __restrict__ ebuf,
                                              int E, int NB) {
    __shared__ int hist[1024], base[1024], off[1024];
    for (int i = threadIdx.x; i < NB; i += 256) hist[i] = 0;
    __syncthreads();
    int e0 = blockIdx.x * CHUNK;
    #pragma unroll 4
    for (int j = 0; j < CHUNK / 256; ++j) {
        int e = e0 + j * 256 + threadIdx.x;
        if (e < E) atomicAdd(&hist[col[e] >> 7], 1);
    }
    __syncthreads();
    for (int i = threadIdx.x; i < NB; i += 256) {
        int h = hist[i];
        base[i] = h ? atomicAdd(&cursor[i], h) : 0;
        off[i] = 0;
    }
    __syncthreads();
    #pragma unroll 4
    for (int j = 0; j < CHUNK / 256; ++j) {
        int e = e0 + j * 256 + threadIdx.x;
        if (e < E) {
            int c = col[e], b = c >> 7;
            int p = base[b] + atomicAdd(&off[b], 1);
            ebuf[p] = make_int2(row[e], c);
        }
    }
}

// ---------------- phase B: per-bucket CSR finalize, all cursors in LDS ----------------

__global__ __launch_bounds__(256) void phaseB(const int2* __restrict__ ebuf, const int* __restrict__ bbase,
                                              int* __restrict__ row_start, int* __restrict__ csr_row,
                                              float* __restrict__ dinv, int N) {
    __shared__ int hist[NPB], sc[NPB], cur[NPB];
    int t = threadIdx.x;
    int node0 = blockIdx.x << 7;
    int e0 = bbase[blockIdx.x], e1 = bbase[blockIdx.x + 1];
    if (t < NPB) hist[t] = 0;
    __syncthreads();
    for (int e = e0 + t; e < e1; e += 256) atomicAdd(&hist[ebuf[e].y & (NPB - 1)], 1);
    __syncthreads();
    if (t < NPB) sc[t] = hist[t];
    __syncthreads();
    for (int off = 1; off < NPB; off <<= 1) {
        int x = (t < NPB && t >= off) ? sc[t - off] : 0;
        __syncthreads();
        if (t < NPB) sc[t] += x;
        __syncthreads();
    }
    if (t < NPB) {
        int start = e0 + sc[t] - hist[t];     // exclusive
        cur[t] = start;
        int n = node0 + t;
        if (n < N) {
            row_start[n] = start;
            dinv[n] = rsqrtf((float)hist[t] + 1.0f);  // +1 = self-loop
        }
    }
    __syncthreads();
    for (int e = e0 + t; e < e1; e += 256) {
        int2 p = ebuf[e];
        int pos = atomicAdd(&cur[p.y & (NPB - 1)], 1);
        csr_row[pos] = p.x;
    }
}

// ---------------- W1 prep: f32 [128][64] -> f16 transposed [64][128] ----------------

__global__ void prep_w1(const float* __restrict__ W1, half_t* __restrict__ W1t) {
    int i = blockIdx.x * 256 + threadIdx.x;
    if (i < F_IN * HID) {
        int k = i >> 6, n = i & 63;
        W1t[n * F_IN + k] = (half_t)W1[i];
    }
}

// ---------------- layer 1 GEMM via MFMA: hs1 = fp16((x @ W1) * dinv[n]) ----------------
// Block = 16 nodes; wave w computes the 16x16 tile (nodes x feats 16w..16w+15), K=128.

__global__ __launch_bounds__(256) void gemm1(
    const float* __restrict__ x, const half_t* __restrict__ W1t,
    const float* __restrict__ dinv, __half* __restrict__ hs1, int N)
{
    __shared__ __align__(16) half_t As[16 * GPAD + 8];   // padded: 2-way-free LDS banks
    int node0 = blockIdx.x * 16;
    size_t total = (size_t)N * F_IN;
    for (int idx = threadIdx.x; idx < 16 * F_IN / 4; idx += 256) {
        int nl = idx >> 5;          // local node
        int k4 = idx & 31;          // float4 within row
        size_t g = (size_t)(node0 + nl) * F_IN + k4 * 4;
        float4 v = make_float4(0.f, 0.f, 0.f, 0.f);
        if (g < total) v = *(const float4*)&x[g];
        half_t* dst = &As[nl * GPAD + k4 * 4];
        dst[0] = (half_t)v.x; dst[1] = (half_t)v.y;
        dst[2] = (half_t)v.z; dst[3] = (half_t)v.w;
    }
    __syncthreads();
    int wv = threadIdx.x >> 6, lane = threadIdx.x & 63;
    int l15 = lane & 15, quad = lane >> 4;
    int fcol = wv * 16 + l15;
    float4v acc = {0.f, 0.f, 0.f, 0.f};
    #pragma unroll
    for (int kb = 0; kb < 4; ++kb) {
        half8 a = *(const half8*)&As[l15 * GPAD + kb * 32 + quad * 8];        // A[m=lane&15][k=quad*8+j]
        half8 b = *(const half8*)&W1t[(size_t)fcol * F_IN + kb * 32 + quad * 8]; // B[k][n=lane&15]
        acc = __builtin_amdgcn_mfma_f32_16x16x32_f16(a, b, acc, 0, 0, 0);
    }
    // C/D: col(n)=lane&15, row(m)=quad*4+reg
    #pragma unroll
    for (int r = 0; r < 4; ++r) {
        int node = node0 + quad * 4 + r;
        if (node < N) hs1[(size_t)node * HID + fcol] = __float2half(acc[r] * dinv[node]);
    }
}

// ---------------- layer-1 gather-aggregate (half2, split-wave) + relu + @W2 (regs) ----------------
// Wave per node. Lane = (h, f2): h = edge-parity half, f2 = feature pair.
// 16 edges in flight per main iteration; W2 column in 16 registers (no LDS).

__global__ __launch_bounds__(256) void agg_l1(
    const __half* __restrict__ hs1, const int* __restrict__ rs,
    const int* __restrict__ csr, const float* __restrict__ dinv,
    const float* __restrict__ b1, const float* __restrict__ W2,
    __half* __restrict__ h2s, int N)
{
    int w = threadIdx.x >> 6, lane = threadIdx.x & 63;
    int c = blockIdx.x * 4 + w;
    if (c >= N) return;
    int h = lane >> 5, f2 = lane & 31;
    int j = lane >> 2, part = lane & 3;          // matvec role: output class j, k-range part
    float w2r[16];
    #pragma unroll
    for (int t = 0; t < 16; ++t) w2r[t] = W2[(part * 16 + t) * NCLS + j];

    const __half2* H = (const __half2*)hs1;      // row stride 32 half2
    float dc = dinv[c];
    float2 sum = make_float2(0.f, 0.f);
    if (h == 0) {                                 // self-loop counted once
        float2 s0 = __half22float2(H[(size_t)c * 32 + f2]);
        sum = s0;
    }
    int e0 = rs[c], e1 = rs[c + 1];
    int i = e0 + h;                               // this half: edges i, i+2, ...
    for (; i + 14 < e1; i += 16) {
        int r0 = csr[i + 0],  r1 = csr[i + 2],  r2 = csr[i + 4],  r3 = csr[i + 6];
        int r4 = csr[i + 8],  r5 = csr[i + 10], r6 = csr[i + 12], r7 = csr[i + 14];
        float2 a0 = __half22float2(H[(size_t)r0 * 32 + f2]);
        float2 a1 = __half22float2(H[(size_t)r1 * 32 + f2]);
        float2 a2 = __half22float2(H[(size_t)r2 * 32 + f2]);
        float2 a3 = __half22float2(H[(size_t)r3 * 32 + f2]);
        float2 a4 = __half22float2(H[(size_t)r4 * 32 + f2]);
        float2 a5 = __half22float2(H[(size_t)r5 * 32 + f2]);
        float2 a6 = __half22float2(H[(size_t)r6 * 32 + f2]);
        float2 a7 = __half22float2(H[(size_t)r7 * 32 + f2]);
        sum.x += ((a0.x + a1.x) + (a2.x + a3.x)) + ((a4.x + a5.x) + (a6.x + a7.x));
        sum.y += ((a0.y + a1.y) + (a2.y + a3.y)) + ((a4.y + a5.y) + (a6.y + a7.y));
    }
    for (; i < e1; i += 2) {
        float2 a = __half22float2(H[(size_t)csr[i] * 32 + f2]);
        sum.x += a.x; sum.y += a.y;
    }
    sum.x += __shfl_xor(sum.x, 32);
    sum.y += __shfl_xor(sum.y, 32);
    float2 bb = ((const float2*)b1)[f2];
    float2 o;
    o.x = fmaxf(fmaf(dc, sum.x, bb.x), 0.f);
    o.y = fmaxf(fmaf(dc, sum.y, bb.y), 0.f);

    // 64 -> 16 matvec: s16 = sum_t o[k] * W2[k][j], k = part*16+t (t even -> o.x, odd -> o.y)
    float s16 = 0.f;
    #pragma unroll
    for (int t = 0; t < 16; t += 2) {
        int src = part * 8 + (t >> 1);           // lane holding feat pair k>>1
        float ox = __shfl(o.x, src, 64);
        float oy = __shfl(o.y, src, 64);
        s16 = fmaf(ox, w2r[t], s16);
        s16 = fmaf(oy, w2r[t + 1], s16);
    }
    s16 += __shfl_xor(s16, 1);
    s16 += __shfl_xor(s16, 2);
    if (part == 0) h2s[(size_t)c * NCLS + j] = __float2half(dc * s16);
}

// ---------------- layer-2 gather-aggregate (half2, split) + log_softmax ----------------
// 16 threads per node: h = edge parity, f2 = class pair.

__global__ __launch_bounds__(256) void agg2_final(
    const __half* __restrict__ h2s, const int* __restrict__ rs,
    const int* __restrict__ csr, const float* __restrict__ dinv,
    const float* __restrict__ b2, float* __restrict__ out, int N)
{
    int tid = blockIdx.x * 256 + threadIdx.x;
    int c = tid >> 4;
    if (c >= N) return;
    int h = (threadIdx.x >> 3) & 1, f2 = threadIdx.x & 7;
    const __half2* H = (const __half2*)h2s;      // row stride 8 half2
    float2 sum = make_float2(0.f, 0.f);
    if (h == 0) sum = __half22float2(H[(size_t)c * 8 + f2]);  // self-loop
    int e0 = rs[c], e1 = rs[c + 1];
    int i = e0 + h;
    for (; i + 6 < e1; i += 8) {
        int r0 = csr[i + 0], r1 = csr[i + 2], r2 = csr[i + 4], r3 = csr[i + 6];
        float2 a0 = __half22float2(H[(size_t)r0 * 8 + f2]);
        float2 a1 = __half22float2(H[(size_t)r1 * 8 + f2]);
        float2 a2 = __half22float2(H[(size_t)r2 * 8 + f2]);
        float2 a3 = __half22float2(H[(size_t)r3 * 8 + f2]);
        sum.x += (a0.x + a1.x) + (a2.x + a3.x);
        sum.y += (a0.y + a1.y) + (a2.y + a3.y);
    }
    for (; i < e1; i += 2) {
        float2 a = __half22float2(H[(size_t)csr[i] * 8 + f2]);
        sum.x += a.x; sum.y += a.y;
    }
    sum.x += __shfl_xor(sum.x, 8, 16);
    sum.y += __shfl_xor(sum.y, 8, 16);
    float dcv = dinv[c];
    float2 bb = ((const float2*)b2)[f2];
    float2 v;
    v.x = fmaf(dcv, sum.x, bb.x);
    v.y = fmaf(dcv, sum.y, bb.y);
    float mx = fmaxf(v.x, v.y);
    #pragma unroll
    for (int m = 1; m < 8; m <<= 1) mx = fmaxf(mx, __shfl_xor(mx, m, 16));
    float s = __expf(v.x - mx) + __expf(v.y - mx);
    #pragma unroll
    for (int m = 1; m < 8; m <<= 1) s += __shfl_xor(s, m, 16);
    float lse = mx + __logf(s);
    if (h == 0) {
        float2 r = make_float2(v.x - lse, v.y - lse);
        ((float2*)out)[(size_t)c * 8 + f2] = r;
    }
}

// ---------------- launch ----------------

extern "C" void kernel_launch(void* const* d_in, const int* in_sizes, int n_in,
                              void* d_out, int out_size, void* d_ws, size_t ws_size,
                              hipStream_t stream) {
    const float* x  = (const float*)d_in[0];
    const int*   ei = (const int*)d_in[1];
    const float* W1 = (const float*)d_in[2];
    const float* b1 = (const float*)d_in[3];
    const float* W2 = (const float*)d_in[4];
    const float* b2 = (const float*)d_in[5];
    float* out = (float*)d_out;

    const int N = in_sizes[0] / F_IN;
    const int E = in_sizes[1] / 2;
    const int* row = ei;        // edge_index[0] = source
    const int* col = ei + E;    // edge_index[1] = destination

    const int NB = (N + NPB - 1) / NPB;          // buckets; must be <= 1024
    size_t Np  = ((size_t)N + 15) & ~(size_t)15;
    size_t Ep  = ((size_t)E + 15) & ~(size_t)15;
    size_t NBp = ((size_t)NB + 15) & ~(size_t)15;

    char* p = (char*)d_ws;
    float*  dinv      = (float*)p;   p += Np * 4;
    __half* hs1       = (__half*)p;  p += Np * HID * 2;
    __half* h2s       = (__half*)p;  p += Np * NCLS * 2;
    half_t* W1t       = (half_t*)p;  p += (size_t)F_IN * HID * 2;
    int*    row_start = (int*)p;     p += (Np + 16) * 4;
    int*    csr_row   = (int*)p;     p += Ep * 4;
    int2*   ebuf      = (int2*)p;    p += Ep * 8;
    int*    btot      = (int*)p;     p += NBp * 4;
    int*    bbase     = (int*)p;     p += (NBp + 16) * 4;
    int*    bcur      = (int*)p;     p += NBp * 4;

    int nblkE = (E + CHUNK - 1) / CHUNK;

    hipMemsetAsync(btot, 0, NBp * sizeof(int), stream);
    bucket_hist<<<nblkE, 256, 0, stream>>>(col, btot, E, NB);
    bucket_scan<<<1, 256, 0, stream>>>(btot, bbase, bcur, row_start, NB, N, E);
    phaseA<<<nblkE, 256, 0, stream>>>(row, col, bcur, ebuf, E, NB);
    phaseB<<<NB, 256, 0, stream>>>(ebuf, bbase, row_start, csr_row, dinv, N);
    prep_w1<<<(F_IN * HID + 255) / 256, 256, 0, stream>>>(W1, W1t);
    gemm1<<<(N + 15) / 16, 256, 0, stream>>>(x, W1t, dinv, hs1, N);
    agg_l1<<<(N + 3) / 4, 256, 0, stream>>>(hs1, row_start, csr_row, dinv, b1, W2, h2s, N);
    agg2_final<<<(int)(((size_t)N * 16 + 255) / 256), 256, 0, stream>>>(h2s, row_start, csr_row, dinv, b2, out, N);
}

// Round 7
// 223.472 us; speedup vs baseline: 8.5595x; 1.2676x over previous
//
#include <hip/hip_runtime.h>
#include <hip/hip_fp16.h>

#define F_IN 128
#define HID  64
#define NCLS 16
#define NPB  128      // nodes per bucket (pow2); bucket = col >> 7
#define CHUNK 8192    // edges per bucket_hist/phaseA block
#define GPAD 136      // padded A-row stride (halfs) for gemm1 LDS

typedef _Float16 half_t;
typedef __attribute__((ext_vector_type(4))) _Float16 half4;
typedef __attribute__((ext_vector_type(8))) _Float16 half8;
typedef __attribute__((ext_vector_type(4))) float float4v;

// ---------------- bucket histogram (LDS, then fire-and-forget global add) ----------------

__global__ __launch_bounds__(256) void bucket_hist(const int* __restrict__ col,
                                                   int* __restrict__ tot, int E, int NB) {
    __shared__ int hist[1024];                    // NB <= 1024 (N <= 131072)
    for (int i = threadIdx.x; i < NB; i += 256) hist[i] = 0;
    __syncthreads();
    int e0 = blockIdx.x * CHUNK;
    #pragma unroll 4
    for (int j = 0; j < CHUNK / 256; ++j) {
        int e = e0 + j * 256 + threadIdx.x;
        if (e < E) atomicAdd(&hist[col[e] >> 7], 1);
    }
    __syncthreads();
    for (int i = threadIdx.x; i < NB; i += 256)
        if (hist[i]) atomicAdd(&tot[i], hist[i]);
}

// ---------------- one-block parallel exclusive scan of bucket totals ----------------

__global__ __launch_bounds__(256) void bucket_scan(const int* __restrict__ tot,
                                                   int* __restrict__ base, int* __restrict__ cursor,
                                                   int* __restrict__ row_start, int NB, int N, int E) {
    __shared__ int s[256];
    int t = threadIdx.x, i0 = t * 4;
    int v0 = (i0 + 0 < NB) ? tot[i0 + 0] : 0;
    int v1 = (i0 + 1 < NB) ? tot[i0 + 1] : 0;
    int v2 = (i0 + 2 < NB) ? tot[i0 + 2] : 0;
    int v3 = (i0 + 3 < NB) ? tot[i0 + 3] : 0;
    int tsum = v0 + v1 + v2 + v3;
    s[t] = tsum;
    __syncthreads();
    for (int off = 1; off < 256; off <<= 1) {
        int x = (t >= off) ? s[t - off] : 0;
        __syncthreads();
        s[t] += x;
        __syncthreads();
    }
    int run = s[t] - tsum;
    if (i0 + 0 < NB) { base[i0 + 0] = run; cursor[i0 + 0] = run; } run += v0;
    if (i0 + 1 < NB) { base[i0 + 1] = run; cursor[i0 + 1] = run; } run += v1;
    if (i0 + 2 < NB) { base[i0 + 2] = run; cursor[i0 + 2] = run; } run += v2;
    if (i0 + 3 < NB) { base[i0 + 3] = run; cursor[i0 + 3] = run; }
    if (t == 0) { base[NB] = E; row_start[N] = E; }
}

// ---------------- phase A: bin edges by bucket; payload packed (row<<7 | local_col) ----------------

__global__ __launch_bounds__(256) void phaseA(const int* __restrict__ row, const int* __restrict__ col,
                                              int* __restrict__ cursor, int* __restrict__ ebuf,
                                              int E, int NB) {
    __shared__ int hist[1024], base[1024], off[1024];
    for (int i = threadIdx.x; i < NB; i += 256) hist[i] = 0;
    __syncthreads();
    int e0 = blockIdx.x * CHUNK;
    #pragma unroll 4
    for (int j = 0; j < CHUNK / 256; ++j) {
        int e = e0 + j * 256 + threadIdx.x;
        if (e < E) atomicAdd(&hist[col[e] >> 7], 1);
    }
    __syncthreads();
    for (int i = threadIdx.x; i < NB; i += 256) {
        int h = hist[i];
        base[i] = h ? atomicAdd(&cursor[i], h) : 0;
        off[i] = 0;
    }
    __syncthreads();
    #pragma unroll 4
    for (int j = 0; j < CHUNK / 256; ++j) {
        int e = e0 + j * 256 + threadIdx.x;
        if (e < E) {
            int c = col[e], b = c >> 7;
            int p = base[b] + atomicAdd(&off[b], 1);
            ebuf[p] = (row[e] << 7) | (c & (NPB - 1));
        }
    }
}

// ---------------- phase B: per-bucket CSR finalize, all cursors in LDS ----------------

__global__ __launch_bounds__(256) void phaseB(const int* __restrict__ ebuf, const int* __restrict__ bbase,
                                              int* __restrict__ row_start, int* __restrict__ csr_row,
                                              float* __restrict__ dinv, int N) {
    __shared__ int hist[NPB], sc[NPB], cur[NPB];
    int t = threadIdx.x;
    int node0 = blockIdx.x << 7;
    int e0 = bbase[blockIdx.x], e1 = bbase[blockIdx.x + 1];
    if (t < NPB) hist[t] = 0;
    __syncthreads();
    for (int e = e0 + t; e < e1; e += 256) atomicAdd(&hist[ebuf[e] & (NPB - 1)], 1);
    __syncthreads();
    if (t < NPB) sc[t] = hist[t];
    __syncthreads();
    for (int off = 1; off < NPB; off <<= 1) {
        int x = (t < NPB && t >= off) ? sc[t - off] : 0;
        __syncthreads();
        if (t < NPB) sc[t] += x;
        __syncthreads();
    }
    if (t < NPB) {
        int start = e0 + sc[t] - hist[t];     // exclusive
        cur[t] = start;
        int n = node0 + t;
        if (n < N) {
            row_start[n] = start;
            dinv[n] = rsqrtf((float)hist[t] + 1.0f);  // +1 = self-loop
        }
    }
    __syncthreads();
    for (int e = e0 + t; e < e1; e += 256) {
        int p = ebuf[e];
        int pos = atomicAdd(&cur[p & (NPB - 1)], 1);
        csr_row[pos] = p >> 7;
    }
}

// ---------------- W1 prep: f32 [128][64] -> f16 transposed [64][128] ----------------

__global__ void prep_w1(const float* __restrict__ W1, half_t* __restrict__ W1t) {
    int i = blockIdx.x * 256 + threadIdx.x;
    if (i < F_IN * HID) {
        int k = i >> 6, n = i & 63;
        W1t[n * F_IN + k] = (half_t)W1[i];
    }
}

// ---------------- layer 1 GEMM via MFMA: hs1 = fp16((x @ W1) * dinv[n]) ----------------

__global__ __launch_bounds__(256) void gemm1(
    const float* __restrict__ x, const half_t* __restrict__ W1t,
    const float* __restrict__ dinv, __half* __restrict__ hs1, int N)
{
    __shared__ __align__(16) half_t As[16 * GPAD + 8];
    int node0 = blockIdx.x * 16;
    size_t total = (size_t)N * F_IN;
    for (int idx = threadIdx.x; idx < 16 * F_IN / 4; idx += 256) {
        int nl = idx >> 5;
        int k4 = idx & 31;
        size_t g = (size_t)(node0 + nl) * F_IN + k4 * 4;
        float4 v = make_float4(0.f, 0.f, 0.f, 0.f);
        if (g < total) v = *(const float4*)&x[g];
        half_t* dst = &As[nl * GPAD + k4 * 4];
        dst[0] = (half_t)v.x; dst[1] = (half_t)v.y;
        dst[2] = (half_t)v.z; dst[3] = (half_t)v.w;
    }
    __syncthreads();
    int wv = threadIdx.x >> 6, lane = threadIdx.x & 63;
    int l15 = lane & 15, quad = lane >> 4;
    int fcol = wv * 16 + l15;
    float4v acc = {0.f, 0.f, 0.f, 0.f};
    #pragma unroll
    for (int kb = 0; kb < 4; ++kb) {
        half8 a = *(const half8*)&As[l15 * GPAD + kb * 32 + quad * 8];
        half8 b = *(const half8*)&W1t[(size_t)fcol * F_IN + kb * 32 + quad * 8];
        acc = __builtin_amdgcn_mfma_f32_16x16x32_f16(a, b, acc, 0, 0, 0);
    }
    #pragma unroll
    for (int r = 0; r < 4; ++r) {
        int node = node0 + quad * 4 + r;
        if (node < N) hs1[(size_t)node * HID + fcol] = __float2half(acc[r] * dinv[node]);
    }
}

// ---------------- layer-1 gather-aggregate + relu + @W2 ----------------
// 16 lanes per node (4 nodes/wave, 16/block). Lane owns 4 feats (8B half4 loads).
// 8 predicated slots per iteration: clamped index + fma-masked accumulate ->
// full MLP on tails, no serial remainder. W2 matvec via conflict-free LDS.

__global__ __launch_bounds__(256) void agg_l1(
    const __half* __restrict__ hs1, const int* __restrict__ rs,
    const int* __restrict__ csr, const float* __restrict__ dinv,
    const float* __restrict__ b1, const float* __restrict__ W2,
    __half* __restrict__ h2s, int N)
{
    __shared__ float W2l[HID * NCLS];     // 4 KB, index k*16+j
    __shared__ float o1[16][65];          // row stride 65: groups hit distinct banks
    for (int i = threadIdx.x; i < HID * NCLS; i += 256) W2l[i] = W2[i];
    __syncthreads();
    int w = threadIdx.x >> 6, lane = threadIdx.x & 63;
    int g = lane >> 4, gl = lane & 15;
    int rowi = w * 4 + g;
    int c = blockIdx.x * 16 + rowi;
    bool active = (c < N);
    int cc = active ? c : 0;
    float dc = dinv[cc];
    int e0 = rs[cc], e1 = rs[cc + 1];
    int e1m1 = e1 - 1;
    const half4* H = (const half4*)hs1;   // 16 half4 per row
    half4 sv = H[(size_t)cc * 16 + gl];   // self-loop
    float4 sum = make_float4((float)sv[0], (float)sv[1], (float)sv[2], (float)sv[3]);
    for (int i = e0; i < e1; i += 8) {
        int id[8];
        #pragma unroll
        for (int s = 0; s < 8; ++s) id[s] = csr[min(i + s, e1m1)];
        half4 a[8];
        #pragma unroll
        for (int s = 0; s < 8; ++s) a[s] = H[(size_t)id[s] * 16 + gl];
        #pragma unroll
        for (int s = 0; s < 8; ++s) {
            float fm = (i + s < e1) ? 1.f : 0.f;
            sum.x = fmaf(fm, (float)a[s][0], sum.x);
            sum.y = fmaf(fm, (float)a[s][1], sum.y);
            sum.z = fmaf(fm, (float)a[s][2], sum.z);
            sum.w = fmaf(fm, (float)a[s][3], sum.w);
        }
    }
    float4 bb = *(const float4*)&b1[gl * 4];
    o1[rowi][gl * 4 + 0] = fmaxf(fmaf(dc, sum.x, bb.x), 0.f);
    o1[rowi][gl * 4 + 1] = fmaxf(fmaf(dc, sum.y, bb.y), 0.f);
    o1[rowi][gl * 4 + 2] = fmaxf(fmaf(dc, sum.z, bb.z), 0.f);
    o1[rowi][gl * 4 + 3] = fmaxf(fmaf(dc, sum.w, bb.w), 0.f);
    // same-wave write->read: compiler inserts lgkmcnt wait; no barrier needed.
    float s16 = 0.f;
    const float* orow = o1[rowi];
    #pragma unroll 8
    for (int k = 0; k < HID; ++k) s16 = fmaf(orow[k], W2l[k * NCLS + gl], s16);
    if (active) h2s[(size_t)c * NCLS + gl] = __float2half(dc * s16);
}

// ---------------- layer-2 gather-aggregate + log_softmax ----------------
// 8 lanes per node (8 nodes/wave, 32/block). Lane owns 2 classes (4B half2 loads).
// Predicated 8-slot gather; softmax via 3x shfl_xor in the 8-lane group.

__global__ __launch_bounds__(256) void agg2_final(
    const __half* __restrict__ h2s, const int* __restrict__ rs,
    const int* __restrict__ csr, const float* __restrict__ dinv,
    const float* __restrict__ b2, float* __restrict__ out, int N)
{
    int lane = threadIdx.x & 63;
    int g = lane >> 3, gl = lane & 7;
    int c = blockIdx.x * 32 + (threadIdx.x >> 6) * 8 + g;
    bool active = (c < N);
    int cc = active ? c : 0;
    float dcv = dinv[cc];
    int e0 = rs[cc], e1 = rs[cc + 1];
    int e1m1 = e1 - 1;
    const __half2* H = (const __half2*)h2s;  // 8 half2 per row
    float2 sum = __half22float2(H[(size_t)cc * 8 + gl]);  // self-loop
    for (int i = e0; i < e1; i += 8) {
        int id[8];
        #pragma unroll
        for (int s = 0; s < 8; ++s) id[s] = csr[min(i + s, e1m1)];
        __half2 a[8];
        #pragma unroll
        for (int s = 0; s < 8; ++s) a[s] = H[(size_t)id[s] * 8 + gl];
        #pragma unroll
        for (int s = 0; s < 8; ++s) {
            float fm = (i + s < e1) ? 1.f : 0.f;
            float2 f2 = __half22float2(a[s]);
            sum.x = fmaf(fm, f2.x, sum.x);
            sum.y = fmaf(fm, f2.y, sum.y);
        }
    }
    float2 bb = ((const float2*)b2)[gl];
    float2 v;
    v.x = fmaf(dcv, sum.x, bb.x);
    v.y = fmaf(dcv, sum.y, bb.y);
    float mx = fmaxf(v.x, v.y);
    mx = fmaxf(mx, __shfl_xor(mx, 1, 64));
    mx = fmaxf(mx, __shfl_xor(mx, 2, 64));
    mx = fmaxf(mx, __shfl_xor(mx, 4, 64));
    float s = __expf(v.x - mx) + __expf(v.y - mx);
    s += __shfl_xor(s, 1, 64);
    s += __shfl_xor(s, 2, 64);
    s += __shfl_xor(s, 4, 64);
    float lse = mx + __logf(s);
    if (active) ((float2*)out)[(size_t)c * 8 + gl] = make_float2(v.x - lse, v.y - lse);
}

// ---------------- launch ----------------

extern "C" void kernel_launch(void* const* d_in, const int* in_sizes, int n_in,
                              void* d_out, int out_size, void* d_ws, size_t ws_size,
                              hipStream_t stream) {
    const float* x  = (const float*)d_in[0];
    const int*   ei = (const int*)d_in[1];
    const float* W1 = (const float*)d_in[2];
    const float* b1 = (const float*)d_in[3];
    const float* W2 = (const float*)d_in[4];
    const float* b2 = (const float*)d_in[5];
    float* out = (float*)d_out;

    const int N = in_sizes[0] / F_IN;
    const int E = in_sizes[1] / 2;
    const int* row = ei;        // edge_index[0] = source
    const int* col = ei + E;    // edge_index[1] = destination

    const int NB = (N + NPB - 1) / NPB;          // buckets; must be <= 1024
    size_t Np  = ((size_t)N + 15) & ~(size_t)15;
    size_t Ep  = ((size_t)E + 15) & ~(size_t)15;
    size_t NBp = ((size_t)NB + 15) & ~(size_t)15;

    char* p = (char*)d_ws;
    float*  dinv      = (float*)p;   p += Np * 4;
    __half* hs1       = (__half*)p;  p += Np * HID * 2;
    __half* h2s       = (__half*)p;  p += Np * NCLS * 2;
    half_t* W1t       = (half_t*)p;  p += (size_t)F_IN * HID * 2;
    int*    row_start = (int*)p;     p += (Np + 16) * 4;
    int*    csr_row   = (int*)p;     p += Ep * 4;
    int*    ebuf      = (int*)p;     p += Ep * 4;
    int*    btot      = (int*)p;     p += NBp * 4;
    int*    bbase     = (int*)p;     p += (NBp + 16) * 4;
    int*    bcur      = (int*)p;     p += NBp * 4;

    int nblkE = (E + CHUNK - 1) / CHUNK;

    hipMemsetAsync(btot, 0, NBp * sizeof(int), stream);
    bucket_hist<<<nblkE, 256, 0, stream>>>(col, btot, E, NB);
    bucket_scan<<<1, 256, 0, stream>>>(btot, bbase, bcur, row_start, NB, N, E);
    phaseA<<<nblkE, 256, 0, stream>>>(row, col, bcur, ebuf, E, NB);
    phaseB<<<NB, 256, 0, stream>>>(ebuf, bbase, row_start, csr_row, dinv, N);
    prep_w1<<<(F_IN * HID + 255) / 256, 256, 0, stream>>>(W1, W1t);
    gemm1<<<(N + 15) / 16, 256, 0, stream>>>(x, W1t, dinv, hs1, N);
    agg_l1<<<(N + 15) / 16, 256, 0, stream>>>(hs1, row_start, csr_row, dinv, b1, W2, h2s, N);
    agg2_final<<<(N + 31) / 32, 256, 0, stream>>>(h2s, row_start, csr_row, dinv, b2, out, N);
}

// Round 8
// 210.453 us; speedup vs baseline: 9.0890x; 1.0619x over previous
//
#include <hip/hip_runtime.h>
#include <hip/hip_fp16.h>

#define F_IN 128
#define HID  64
#define NCLS 16
#define NPB  128      // nodes per bucket (pow2); bucket = col >> 7
#define CHUNK 4096    // edges per bucket_hist/phaseA block
#define BINTHREADS 1024
#define GPAD 136      // padded A-row stride (halfs) for gemm1 LDS

typedef _Float16 half_t;
typedef __attribute__((ext_vector_type(4))) _Float16 half4;
typedef __attribute__((ext_vector_type(8))) _Float16 half8;
typedef __attribute__((ext_vector_type(4))) float float4v;

// ---------------- bucket histogram (LDS, then fire-and-forget global add) ----------------

__global__ __launch_bounds__(BINTHREADS) void bucket_hist(const int* __restrict__ col,
                                                          int* __restrict__ tot, int E, int NB) {
    __shared__ int hist[1024];                    // NB <= 1024 (N <= 131072)
    for (int i = threadIdx.x; i < NB; i += BINTHREADS) hist[i] = 0;
    __syncthreads();
    int e0 = blockIdx.x * CHUNK;
    #pragma unroll
    for (int j = 0; j < CHUNK / BINTHREADS; ++j) {
        int e = e0 + j * BINTHREADS + threadIdx.x;
        if (e < E) atomicAdd(&hist[col[e] >> 7], 1);
    }
    __syncthreads();
    for (int i = threadIdx.x; i < NB; i += BINTHREADS)
        if (hist[i]) atomicAdd(&tot[i], hist[i]);
}

// ---------------- one-block parallel exclusive scan of bucket totals ----------------

__global__ __launch_bounds__(256) void bucket_scan(const int* __restrict__ tot,
                                                   int* __restrict__ base, int* __restrict__ cursor,
                                                   int* __restrict__ row_start, int NB, int N, int E) {
    __shared__ int s[256];
    int t = threadIdx.x, i0 = t * 4;
    int v0 = (i0 + 0 < NB) ? tot[i0 + 0] : 0;
    int v1 = (i0 + 1 < NB) ? tot[i0 + 1] : 0;
    int v2 = (i0 + 2 < NB) ? tot[i0 + 2] : 0;
    int v3 = (i0 + 3 < NB) ? tot[i0 + 3] : 0;
    int tsum = v0 + v1 + v2 + v3;
    s[t] = tsum;
    __syncthreads();
    for (int off = 1; off < 256; off <<= 1) {
        int x = (t >= off) ? s[t - off] : 0;
        __syncthreads();
        s[t] += x;
        __syncthreads();
    }
    int run = s[t] - tsum;
    if (i0 + 0 < NB) { base[i0 + 0] = run; cursor[i0 + 0] = run; } run += v0;
    if (i0 + 1 < NB) { base[i0 + 1] = run; cursor[i0 + 1] = run; } run += v1;
    if (i0 + 2 < NB) { base[i0 + 2] = run; cursor[i0 + 2] = run; } run += v2;
    if (i0 + 3 < NB) { base[i0 + 3] = run; cursor[i0 + 3] = run; }
    if (t == 0) { base[NB] = E; row_start[N] = E; }
}

// ---------------- phase A: bin edges by bucket; payload packed (row<<7 | local_col) ----------------

__global__ __launch_bounds__(BINTHREADS) void phaseA(const int* __restrict__ row, const int* __restrict__ col,
                                                     int* __restrict__ cursor, int* __restrict__ ebuf,
                                                     int E, int NB) {
    __shared__ int hist[1024], base[1024], off[1024];
    for (int i = threadIdx.x; i < NB; i += BINTHREADS) hist[i] = 0;
    __syncthreads();
    int e0 = blockIdx.x * CHUNK;
    #pragma unroll
    for (int j = 0; j < CHUNK / BINTHREADS; ++j) {
        int e = e0 + j * BINTHREADS + threadIdx.x;
        if (e < E) atomicAdd(&hist[col[e] >> 7], 1);
    }
    __syncthreads();
    for (int i = threadIdx.x; i < NB; i += BINTHREADS) {
        int h = hist[i];
        base[i] = h ? atomicAdd(&cursor[i], h) : 0;
        off[i] = 0;
    }
    __syncthreads();
    #pragma unroll
    for (int j = 0; j < CHUNK / BINTHREADS; ++j) {
        int e = e0 + j * BINTHREADS + threadIdx.x;
        if (e < E) {
            int c = col[e], b = c >> 7;
            int p = base[b] + atomicAdd(&off[b], 1);
            ebuf[p] = (row[e] << 7) | (c & (NPB - 1));
        }
    }
}

// ---------------- phase B: per-bucket CSR finalize, all cursors in LDS ----------------

__global__ __launch_bounds__(256) void phaseB(const int* __restrict__ ebuf, const int* __restrict__ bbase,
                                              int* __restrict__ row_start, int* __restrict__ csr_row,
                                              float* __restrict__ dinv, int N) {
    __shared__ int hist[NPB], sc[NPB], cur[NPB];
    int t = threadIdx.x;
    int node0 = blockIdx.x << 7;
    int e0 = bbase[blockIdx.x], e1 = bbase[blockIdx.x + 1];
    if (t < NPB) hist[t] = 0;
    __syncthreads();
    for (int e = e0 + t; e < e1; e += 256) atomicAdd(&hist[ebuf[e] & (NPB - 1)], 1);
    __syncthreads();
    if (t < NPB) sc[t] = hist[t];
    __syncthreads();
    for (int off = 1; off < NPB; off <<= 1) {
        int x = (t < NPB && t >= off) ? sc[t - off] : 0;
        __syncthreads();
        if (t < NPB) sc[t] += x;
        __syncthreads();
    }
    if (t < NPB) {
        int start = e0 + sc[t] - hist[t];     // exclusive
        cur[t] = start;
        int n = node0 + t;
        if (n < N) {
            row_start[n] = start;
            dinv[n] = rsqrtf((float)hist[t] + 1.0f);  // +1 = self-loop
        }
    }
    __syncthreads();
    for (int e = e0 + t; e < e1; e += 256) {
        int p = ebuf[e];
        int pos = atomicAdd(&cur[p & (NPB - 1)], 1);
        csr_row[pos] = p >> 7;
    }
}

// ---------------- W1 prep: f32 [128][64] -> f16 transposed [64][128] ----------------

__global__ void prep_w1(const float* __restrict__ W1, half_t* __restrict__ W1t) {
    int i = blockIdx.x * 256 + threadIdx.x;
    if (i < F_IN * HID) {
        int k = i >> 6, n = i & 63;
        W1t[n * F_IN + k] = (half_t)W1[i];
    }
}

// ---------------- layer 1 GEMM via MFMA: hs1 = fp16((x @ W1) * dinv[n]) ----------------

__global__ __launch_bounds__(256) void gemm1(
    const float* __restrict__ x, const half_t* __restrict__ W1t,
    const float* __restrict__ dinv, __half* __restrict__ hs1, int N)
{
    __shared__ __align__(16) half_t As[16 * GPAD + 8];
    int node0 = blockIdx.x * 16;
    size_t total = (size_t)N * F_IN;
    for (int idx = threadIdx.x; idx < 16 * F_IN / 4; idx += 256) {
        int nl = idx >> 5;
        int k4 = idx & 31;
        size_t g = (size_t)(node0 + nl) * F_IN + k4 * 4;
        float4 v = make_float4(0.f, 0.f, 0.f, 0.f);
        if (g < total) v = *(const float4*)&x[g];
        half_t* dst = &As[nl * GPAD + k4 * 4];
        dst[0] = (half_t)v.x; dst[1] = (half_t)v.y;
        dst[2] = (half_t)v.z; dst[3] = (half_t)v.w;
    }
    __syncthreads();
    int wv = threadIdx.x >> 6, lane = threadIdx.x & 63;
    int l15 = lane & 15, quad = lane >> 4;
    int fcol = wv * 16 + l15;
    float4v acc = {0.f, 0.f, 0.f, 0.f};
    #pragma unroll
    for (int kb = 0; kb < 4; ++kb) {
        half8 a = *(const half8*)&As[l15 * GPAD + kb * 32 + quad * 8];
        half8 b = *(const half8*)&W1t[(size_t)fcol * F_IN + kb * 32 + quad * 8];
        acc = __builtin_amdgcn_mfma_f32_16x16x32_f16(a, b, acc, 0, 0, 0);
    }
    #pragma unroll
    for (int r = 0; r < 4; ++r) {
        int node = node0 + quad * 4 + r;
        if (node < N) hs1[(size_t)node * HID + fcol] = __float2half(acc[r] * dinv[node]);
    }
}

// ---------------- layer-1 gather-aggregate + relu + @W2 ----------------
// 16 lanes per node (4 nodes/wave, 16/block). Lane owns 4 feats (8B half4 loads).
// 8 predicated slots per iteration; W2 matvec via conflict-free LDS.

__global__ __launch_bounds__(256) void agg_l1(
    const __half* __restrict__ hs1, const int* __restrict__ rs,
    const int* __restrict__ csr, const float* __restrict__ dinv,
    const float* __restrict__ b1, const float* __restrict__ W2,
    __half* __restrict__ h2s, int N)
{
    __shared__ float W2l[HID * NCLS];     // 4 KB, index k*16+j
    __shared__ float o1[16][65];          // row stride 65: groups hit distinct banks
    for (int i = threadIdx.x; i < HID * NCLS; i += 256) W2l[i] = W2[i];
    __syncthreads();
    int w = threadIdx.x >> 6, lane = threadIdx.x & 63;
    int g = lane >> 4, gl = lane & 15;
    int rowi = w * 4 + g;
    int c = blockIdx.x * 16 + rowi;
    bool active = (c < N);
    int cc = active ? c : 0;
    float dc = dinv[cc];
    int e0 = rs[cc], e1 = rs[cc + 1];
    int e1m1 = e1 - 1;
    const half4* H = (const half4*)hs1;   // 16 half4 per row
    half4 sv = H[(size_t)cc * 16 + gl];   // self-loop
    float4 sum = make_float4((float)sv[0], (float)sv[1], (float)sv[2], (float)sv[3]);
    for (int i = e0; i < e1; i += 8) {
        int id[8];
        #pragma unroll
        for (int s = 0; s < 8; ++s) id[s] = csr[min(i + s, e1m1)];
        half4 a[8];
        #pragma unroll
        for (int s = 0; s < 8; ++s) a[s] = H[(size_t)id[s] * 16 + gl];
        #pragma unroll
        for (int s = 0; s < 8; ++s) {
            float fm = (i + s < e1) ? 1.f : 0.f;
            sum.x = fmaf(fm, (float)a[s][0], sum.x);
            sum.y = fmaf(fm, (float)a[s][1], sum.y);
            sum.z = fmaf(fm, (float)a[s][2], sum.z);
            sum.w = fmaf(fm, (float)a[s][3], sum.w);
        }
    }
    float4 bb = *(const float4*)&b1[gl * 4];
    o1[rowi][gl * 4 + 0] = fmaxf(fmaf(dc, sum.x, bb.x), 0.f);
    o1[rowi][gl * 4 + 1] = fmaxf(fmaf(dc, sum.y, bb.y), 0.f);
    o1[rowi][gl * 4 + 2] = fmaxf(fmaf(dc, sum.z, bb.z), 0.f);
    o1[rowi][gl * 4 + 3] = fmaxf(fmaf(dc, sum.w, bb.w), 0.f);
    // same-wave write->read: compiler inserts lgkmcnt wait; no barrier needed.
    float s16 = 0.f;
    const float* orow = o1[rowi];
    #pragma unroll 8
    for (int k = 0; k < HID; ++k) s16 = fmaf(orow[k], W2l[k * NCLS + gl], s16);
    if (active) h2s[(size_t)c * NCLS + gl] = __float2half(dc * s16);
}

// ---------------- layer-2 gather-aggregate + log_softmax ----------------
// 8 lanes per node (8 nodes/wave, 32/block). Predicated 8-slot gather.

__global__ __launch_bounds__(256) void agg2_final(
    const __half* __restrict__ h2s, const int* __restrict__ rs,
    const int* __restrict__ csr, const float* __restrict__ dinv,
    const float* __restrict__ b2, float* __restrict__ out, int N)
{
    int lane = threadIdx.x & 63;
    int g = lane >> 3, gl = lane & 7;
    int c = blockIdx.x * 32 + (threadIdx.x >> 6) * 8 + g;
    bool active = (c < N);
    int cc = active ? c : 0;
    float dcv = dinv[cc];
    int e0 = rs[cc], e1 = rs[cc + 1];
    int e1m1 = e1 - 1;
    const __half2* H = (const __half2*)h2s;  // 8 half2 per row
    float2 sum = __half22float2(H[(size_t)cc * 8 + gl]);  // self-loop
    for (int i = e0; i < e1; i += 8) {
        int id[8];
        #pragma unroll
        for (int s = 0; s < 8; ++s) id[s] = csr[min(i + s, e1m1)];
        __half2 a[8];
        #pragma unroll
        for (int s = 0; s < 8; ++s) a[s] = H[(size_t)id[s] * 8 + gl];
        #pragma unroll
        for (int s = 0; s < 8; ++s) {
            float fm = (i + s < e1) ? 1.f : 0.f;
            float2 f2 = __half22float2(a[s]);
            sum.x = fmaf(fm, f2.x, sum.x);
            sum.y = fmaf(fm, f2.y, sum.y);
        }
    }
    float2 bb = ((const float2*)b2)[gl];
    float2 v;
    v.x = fmaf(dcv, sum.x, bb.x);
    v.y = fmaf(dcv, sum.y, bb.y);
    float mx = fmaxf(v.x, v.y);
    mx = fmaxf(mx, __shfl_xor(mx, 1, 64));
    mx = fmaxf(mx, __shfl_xor(mx, 2, 64));
    mx = fmaxf(mx, __shfl_xor(mx, 4, 64));
    float s = __expf(v.x - mx) + __expf(v.y - mx);
    s += __shfl_xor(s, 1, 64);
    s += __shfl_xor(s, 2, 64);
    s += __shfl_xor(s, 4, 64);
    float lse = mx + __logf(s);
    if (active) ((float2*)out)[(size_t)c * 8 + gl] = make_float2(v.x - lse, v.y - lse);
}

// ---------------- launch ----------------

extern "C" void kernel_launch(void* const* d_in, const int* in_sizes, int n_in,
                              void* d_out, int out_size, void* d_ws, size_t ws_size,
                              hipStream_t stream) {
    const float* x  = (const float*)d_in[0];
    const int*   ei = (const int*)d_in[1];
    const float* W1 = (const float*)d_in[2];
    const float* b1 = (const float*)d_in[3];
    const float* W2 = (const float*)d_in[4];
    const float* b2 = (const float*)d_in[5];
    float* out = (float*)d_out;

    const int N = in_sizes[0] / F_IN;
    const int E = in_sizes[1] / 2;
    const int* row = ei;        // edge_index[0] = source
    const int* col = ei + E;    // edge_index[1] = destination

    const int NB = (N + NPB - 1) / NPB;          // buckets; must be <= 1024
    size_t Np  = ((size_t)N + 15) & ~(size_t)15;
    size_t Ep  = ((size_t)E + 15) & ~(size_t)15;
    size_t NBp = ((size_t)NB + 15) & ~(size_t)15;

    char* p = (char*)d_ws;
    float*  dinv      = (float*)p;   p += Np * 4;
    __half* hs1       = (__half*)p;  p += Np * HID * 2;
    __half* h2s       = (__half*)p;  p += Np * NCLS * 2;
    half_t* W1t       = (half_t*)p;  p += (size_t)F_IN * HID * 2;
    int*    row_start = (int*)p;     p += (Np + 16) * 4;
    int*    csr_row   = (int*)p;     p += Ep * 4;
    int*    ebuf      = (int*)p;     p += Ep * 4;
    int*    btot      = (int*)p;     p += NBp * 4;
    int*    bbase     = (int*)p;     p += (NBp + 16) * 4;
    int*    bcur      = (int*)p;     p += NBp * 4;

    int nblkE = (E + CHUNK - 1) / CHUNK;

    hipMemsetAsync(btot, 0, NBp * sizeof(int), stream);
    bucket_hist<<<nblkE, BINTHREADS, 0, stream>>>(col, btot, E, NB);
    bucket_scan<<<1, 256, 0, stream>>>(btot, bbase, bcur, row_start, NB, N, E);
    phaseA<<<nblkE, BINTHREADS, 0, stream>>>(row, col, bcur, ebuf, E, NB);
    phaseB<<<NB, 256, 0, stream>>>(ebuf, bbase, row_start, csr_row, dinv, N);
    prep_w1<<<(F_IN * HID + 255) / 256, 256, 0, stream>>>(W1, W1t);
    gemm1<<<(N + 15) / 16, 256, 0, stream>>>(x, W1t, dinv, hs1, N);
    agg_l1<<<(N + 15) / 16, 256, 0, stream>>>(hs1, row_start, csr_row, dinv, b1, W2, h2s, N);
    agg2_final<<<(N + 31) / 32, 256, 0, stream>>>(h2s, row_start, csr_row, dinv, b2, out, N);
}

// Round 9
// 207.237 us; speedup vs baseline: 9.2301x; 1.0155x over previous
//
#include <hip/hip_runtime.h>
#include <hip/hip_fp16.h>

#define F_IN 128
#define HID  64
#define NCLS 16
#define NPB  128      // nodes per bucket (pow2); bucket = col >> 7
#define CHUNK 4096    // edges per bucket_hist/phaseA block
#define BINTHREADS 1024
#define GPAD 136      // padded A-row stride (halfs) for gemm1 LDS

typedef _Float16 half_t;
typedef __attribute__((ext_vector_type(8))) _Float16 half8;
typedef __attribute__((ext_vector_type(4))) float float4v;

// ---------------- bucket histogram + (fused) W1 prep ----------------
// Blocks [0, nblkE): LDS histogram of col>>7, fire-and-forget global adds.
// Block nblkE: converts W1 f32 [128][64] -> f16 transposed [64][128].

__global__ __launch_bounds__(BINTHREADS) void bucket_hist(
    const int* __restrict__ col, int* __restrict__ tot, int E, int NB,
    const float* __restrict__ W1, half_t* __restrict__ W1t, int nblkE)
{
    if ((int)blockIdx.x >= nblkE) {               // W1 prep block
        for (int i = threadIdx.x; i < F_IN * HID; i += BINTHREADS) {
            int k = i >> 6, n = i & 63;
            W1t[n * F_IN + k] = (half_t)W1[i];
        }
        return;
    }
    __shared__ int hist[1024];                    // NB <= 1024 (N <= 131072)
    for (int i = threadIdx.x; i < NB; i += BINTHREADS) hist[i] = 0;
    __syncthreads();
    int e0 = blockIdx.x * CHUNK;
    #pragma unroll
    for (int j = 0; j < CHUNK / BINTHREADS; ++j) {
        int e = e0 + j * BINTHREADS + threadIdx.x;
        if (e < E) atomicAdd(&hist[col[e] >> 7], 1);
    }
    __syncthreads();
    for (int i = threadIdx.x; i < NB; i += BINTHREADS)
        if (hist[i]) atomicAdd(&tot[i], hist[i]);
}

// ---------------- one-block parallel exclusive scan of bucket totals ----------------

__global__ __launch_bounds__(256) void bucket_scan(const int* __restrict__ tot,
                                                   int* __restrict__ base, int* __restrict__ cursor,
                                                   int* __restrict__ row_start, int NB, int N, int E) {
    __shared__ int s[256];
    int t = threadIdx.x, i0 = t * 4;
    int v0 = (i0 + 0 < NB) ? tot[i0 + 0] : 0;
    int v1 = (i0 + 1 < NB) ? tot[i0 + 1] : 0;
    int v2 = (i0 + 2 < NB) ? tot[i0 + 2] : 0;
    int v3 = (i0 + 3 < NB) ? tot[i0 + 3] : 0;
    int tsum = v0 + v1 + v2 + v3;
    s[t] = tsum;
    __syncthreads();
    for (int off = 1; off < 256; off <<= 1) {
        int x = (t >= off) ? s[t - off] : 0;
        __syncthreads();
        s[t] += x;
        __syncthreads();
    }
    int run = s[t] - tsum;
    if (i0 + 0 < NB) { base[i0 + 0] = run; cursor[i0 + 0] = run; } run += v0;
    if (i0 + 1 < NB) { base[i0 + 1] = run; cursor[i0 + 1] = run; } run += v1;
    if (i0 + 2 < NB) { base[i0 + 2] = run; cursor[i0 + 2] = run; } run += v2;
    if (i0 + 3 < NB) { base[i0 + 3] = run; cursor[i0 + 3] = run; }
    if (t == 0) { base[NB] = E; row_start[N] = E; }
}

// ---------------- phase A: bin edges by bucket; payload packed (row<<7 | local_col) ----------------

__global__ __launch_bounds__(BINTHREADS) void phaseA(const int* __restrict__ row, const int* __restrict__ col,
                                                     int* __restrict__ cursor, int* __restrict__ ebuf,
                                                     int E, int NB) {
    __shared__ int hist[1024], base[1024], off[1024];
    for (int i = threadIdx.x; i < NB; i += BINTHREADS) hist[i] = 0;
    __syncthreads();
    int e0 = blockIdx.x * CHUNK;
    #pragma unroll
    for (int j = 0; j < CHUNK / BINTHREADS; ++j) {
        int e = e0 + j * BINTHREADS + threadIdx.x;
        if (e < E) atomicAdd(&hist[col[e] >> 7], 1);
    }
    __syncthreads();
    for (int i = threadIdx.x; i < NB; i += BINTHREADS) {
        int h = hist[i];
        base[i] = h ? atomicAdd(&cursor[i], h) : 0;
        off[i] = 0;
    }
    __syncthreads();
    #pragma unroll
    for (int j = 0; j < CHUNK / BINTHREADS; ++j) {
        int e = e0 + j * BINTHREADS + threadIdx.x;
        if (e < E) {
            int c = col[e], b = c >> 7;
            int p = base[b] + atomicAdd(&off[b], 1);
            ebuf[p] = (row[e] << 7) | (c & (NPB - 1));
        }
    }
}

// ---------------- phase B: per-bucket CSR finalize; shfl scan, cursors in LDS ----------------

__global__ __launch_bounds__(256) void phaseB(const int* __restrict__ ebuf, const int* __restrict__ bbase,
                                              int* __restrict__ row_start, int* __restrict__ csr_row,
                                              float* __restrict__ dinv, int N) {
    __shared__ int hist[NPB], cur[NPB];
    __shared__ int wtot;
    int t = threadIdx.x;
    int node0 = blockIdx.x << 7;
    int e0 = bbase[blockIdx.x], e1 = bbase[blockIdx.x + 1];
    if (t < NPB) hist[t] = 0;
    __syncthreads();
    for (int e = e0 + t; e < e1; e += 256) atomicAdd(&hist[ebuf[e] & (NPB - 1)], 1);
    __syncthreads();
    int h = 0, incl = 0;
    if (t < NPB) {                         // waves 0,1 fully active
        h = hist[t];
        incl = h;
        #pragma unroll
        for (int off = 1; off < 64; off <<= 1) {
            int u = __shfl_up(incl, off, 64);
            if ((t & 63) >= off) incl += u;
        }
        if (t == 63) wtot = incl;
    }
    __syncthreads();
    if (t < NPB) {
        if (t >= 64) incl += wtot;
        int start = e0 + incl - h;         // exclusive
        cur[t] = start;
        int n = node0 + t;
        if (n < N) {
            row_start[n] = start;
            dinv[n] = rsqrtf((float)h + 1.0f);   // +1 = self-loop
        }
    }
    __syncthreads();
    for (int e = e0 + t; e < e1; e += 256) {
        int p = ebuf[e];
        int pos = atomicAdd(&cur[p & (NPB - 1)], 1);
        csr_row[pos] = p >> 7;
    }
}

// ---------------- layer 1 GEMM via MFMA: hs1 = fp16((x @ W1) * dinv[n]) ----------------
// 32 nodes/block; wave w covers feat cols 16w..16w+15 for both 16-node halves
// (B-fragments reused across the two MFMA chains).

__global__ __launch_bounds__(256) void gemm1(
    const float* __restrict__ x, const half_t* __restrict__ W1t,
    const float* __restrict__ dinv, __half* __restrict__ hs1, int N)
{
    __shared__ __align__(16) half_t As[32 * GPAD + 8];
    int node0 = blockIdx.x * 32;
    size_t total = (size_t)N * F_IN;
    for (int idx = threadIdx.x; idx < 32 * F_IN / 4; idx += 256) {
        int nl = idx >> 5;
        int k4 = idx & 31;
        size_t g = (size_t)(node0 + nl) * F_IN + k4 * 4;
        float4 v = make_float4(0.f, 0.f, 0.f, 0.f);
        if (g < total) v = *(const float4*)&x[g];
        half_t* dst = &As[nl * GPAD + k4 * 4];
        dst[0] = (half_t)v.x; dst[1] = (half_t)v.y;
        dst[2] = (half_t)v.z; dst[3] = (half_t)v.w;
    }
    __syncthreads();
    int wv = threadIdx.x >> 6, lane = threadIdx.x & 63;
    int l15 = lane & 15, quad = lane >> 4;
    int fcol = wv * 16 + l15;
    float4v acc0 = {0.f, 0.f, 0.f, 0.f};
    float4v acc1 = {0.f, 0.f, 0.f, 0.f};
    #pragma unroll
    for (int kb = 0; kb < 4; ++kb) {
        half8 b  = *(const half8*)&W1t[(size_t)fcol * F_IN + kb * 32 + quad * 8];
        half8 a0 = *(const half8*)&As[l15 * GPAD + kb * 32 + quad * 8];
        half8 a1 = *(const half8*)&As[(16 + l15) * GPAD + kb * 32 + quad * 8];
        acc0 = __builtin_amdgcn_mfma_f32_16x16x32_f16(a0, b, acc0, 0, 0, 0);
        acc1 = __builtin_amdgcn_mfma_f32_16x16x32_f16(a1, b, acc1, 0, 0, 0);
    }
    #pragma unroll
    for (int r = 0; r < 4; ++r) {
        int n0 = node0 + quad * 4 + r;
        int n1 = n0 + 16;
        if (n0 < N) hs1[(size_t)n0 * HID + fcol] = __float2half(acc0[r] * dinv[n0]);
        if (n1 < N) hs1[(size_t)n1 * HID + fcol] = __float2half(acc1[r] * dinv[n1]);
    }
}

// ---------------- layer-1 gather-aggregate + relu + @W2 ----------------
// 8 lanes per node (8 nodes/wave, 32/block). Lane owns 8 feats: one half8
// (16B) gather per edge -> 1KB/wave-instr. 8 predicated slots per iteration.
// W2 matvec via conflict-free LDS (o1 stride 65); each lane -> 2 classes.

__global__ __launch_bounds__(256) void agg_l1(
    const __half* __restrict__ hs1, const int* __restrict__ rs,
    const int* __restrict__ csr, const float* __restrict__ dinv,
    const float* __restrict__ b1, const float* __restrict__ W2,
    __half* __restrict__ h2s, int N)
{
    __shared__ float W2l[HID * NCLS];     // 4 KB, index k*16+j
    __shared__ float o1[32][65];          // stride 65: wave's 8 rows on distinct banks
    for (int i = threadIdx.x; i < HID * NCLS; i += 256) W2l[i] = W2[i];
    __syncthreads();
    int w = threadIdx.x >> 6, lane = threadIdx.x & 63;
    int g = lane >> 3, gl = lane & 7;
    int rowi = w * 8 + g;
    int c = blockIdx.x * 32 + rowi;
    bool active = (c < N);
    int cc = active ? c : 0;
    float dc = dinv[cc];
    int e0 = rs[cc], e1 = rs[cc + 1];
    int e1m1 = e1 - 1;
    const half8* H = (const half8*)hs1;   // 8 half8 per row
    half8 sv = H[(size_t)cc * 8 + gl];    // self-loop
    float sum[8];
    #pragma unroll
    for (int k = 0; k < 8; ++k) sum[k] = (float)sv[k];
    for (int i = e0; i < e1; i += 8) {
        int id[8];
        #pragma unroll
        for (int s = 0; s < 8; ++s) id[s] = csr[min(i + s, e1m1)];
        half8 a[8];
        #pragma unroll
        for (int s = 0; s < 8; ++s) a[s] = H[(size_t)id[s] * 8 + gl];
        #pragma unroll
        for (int s = 0; s < 8; ++s) {
            float fm = (i + s < e1) ? 1.f : 0.f;
            #pragma unroll
            for (int k = 0; k < 8; ++k) sum[k] = fmaf(fm, (float)a[s][k], sum[k]);
        }
    }
    float4 bb0 = *(const float4*)&b1[gl * 8];
    float4 bb1 = *(const float4*)&b1[gl * 8 + 4];
    o1[rowi][gl * 8 + 0] = fmaxf(fmaf(dc, sum[0], bb0.x), 0.f);
    o1[rowi][gl * 8 + 1] = fmaxf(fmaf(dc, sum[1], bb0.y), 0.f);
    o1[rowi][gl * 8 + 2] = fmaxf(fmaf(dc, sum[2], bb0.z), 0.f);
    o1[rowi][gl * 8 + 3] = fmaxf(fmaf(dc, sum[3], bb0.w), 0.f);
    o1[rowi][gl * 8 + 4] = fmaxf(fmaf(dc, sum[4], bb1.x), 0.f);
    o1[rowi][gl * 8 + 5] = fmaxf(fmaf(dc, sum[5], bb1.y), 0.f);
    o1[rowi][gl * 8 + 6] = fmaxf(fmaf(dc, sum[6], bb1.z), 0.f);
    o1[rowi][gl * 8 + 7] = fmaxf(fmaf(dc, sum[7], bb1.w), 0.f);
    // same-wave LDS write->read: compiler inserts lgkmcnt wait; no barrier.
    int j0 = gl * 2, j1 = gl * 2 + 1;
    float s0 = 0.f, s1 = 0.f;
    const float* orow = o1[rowi];
    #pragma unroll 8
    for (int k = 0; k < HID; ++k) {
        float ov = orow[k];
        s0 = fmaf(ov, W2l[k * NCLS + j0], s0);
        s1 = fmaf(ov, W2l[k * NCLS + j1], s1);
    }
    if (active) {
        __half2 hv;
        hv.x = __float2half(dc * s0);
        hv.y = __float2half(dc * s1);
        ((__half2*)h2s)[(size_t)c * 8 + gl] = hv;
    }
}

// ---------------- layer-2 gather-aggregate + log_softmax ----------------
// 8 lanes per node (8 nodes/wave, 32/block). Predicated 8-slot gather.

__global__ __launch_bounds__(256) void agg2_final(
    const __half* __restrict__ h2s, const int* __restrict__ rs,
    const int* __restrict__ csr, const float* __restrict__ dinv,
    const float* __restrict__ b2, float* __restrict__ out, int N)
{
    int lane = threadIdx.x & 63;
    int g = lane >> 3, gl = lane & 7;
    int c = blockIdx.x * 32 + (threadIdx.x >> 6) * 8 + g;
    bool active = (c < N);
    int cc = active ? c : 0;
    float dcv = dinv[cc];
    int e0 = rs[cc], e1 = rs[cc + 1];
    int e1m1 = e1 - 1;
    const __half2* H = (const __half2*)h2s;  // 8 half2 per row
    float2 sum = __half22float2(H[(size_t)cc * 8 + gl]);  // self-loop
    for (int i = e0; i < e1; i += 8) {
        int id[8];
        #pragma unroll
        for (int s = 0; s < 8; ++s) id[s] = csr[min(i + s, e1m1)];
        __half2 a[8];
        #pragma unroll
        for (int s = 0; s < 8; ++s) a[s] = H[(size_t)id[s] * 8 + gl];
        #pragma unroll
        for (int s = 0; s < 8; ++s) {
            float fm = (i + s < e1) ? 1.f : 0.f;
            float2 f2 = __half22float2(a[s]);
            sum.x = fmaf(fm, f2.x, sum.x);
            sum.y = fmaf(fm, f2.y, sum.y);
        }
    }
    float2 bb = ((const float2*)b2)[gl];
    float2 v;
    v.x = fmaf(dcv, sum.x, bb.x);
    v.y = fmaf(dcv, sum.y, bb.y);
    float mx = fmaxf(v.x, v.y);
    mx = fmaxf(mx, __shfl_xor(mx, 1, 64));
    mx = fmaxf(mx, __shfl_xor(mx, 2, 64));
    mx = fmaxf(mx, __shfl_xor(mx, 4, 64));
    float s = __expf(v.x - mx) + __expf(v.y - mx);
    s += __shfl_xor(s, 1, 64);
    s += __shfl_xor(s, 2, 64);
    s += __shfl_xor(s, 4, 64);
    float lse = mx + __logf(s);
    if (active) ((float2*)out)[(size_t)c * 8 + gl] = make_float2(v.x - lse, v.y - lse);
}

// ---------------- launch ----------------

extern "C" void kernel_launch(void* const* d_in, const int* in_sizes, int n_in,
                              void* d_out, int out_size, void* d_ws, size_t ws_size,
                              hipStream_t stream) {
    const float* x  = (const float*)d_in[0];
    const int*   ei = (const int*)d_in[1];
    const float* W1 = (const float*)d_in[2];
    const float* b1 = (const float*)d_in[3];
    const float* W2 = (const float*)d_in[4];
    const float* b2 = (const float*)d_in[5];
    float* out = (float*)d_out;

    const int N = in_sizes[0] / F_IN;
    const int E = in_sizes[1] / 2;
    const int* row = ei;        // edge_index[0] = source
    const int* col = ei + E;    // edge_index[1] = destination

    const int NB = (N + NPB - 1) / NPB;          // buckets; must be <= 1024
    size_t Np  = ((size_t)N + 15) & ~(size_t)15;
    size_t Ep  = ((size_t)E + 15) & ~(size_t)15;
    size_t NBp = ((size_t)NB + 15) & ~(size_t)15;

    char* p = (char*)d_ws;
    float*  dinv      = (float*)p;   p += Np * 4;
    __half* hs1       = (__half*)p;  p += Np * HID * 2;
    __half* h2s       = (__half*)p;  p += Np * NCLS * 2;
    half_t* W1t       = (half_t*)p;  p += (size_t)F_IN * HID * 2;
    int*    row_start = (int*)p;     p += (Np + 16) * 4;
    int*    csr_row   = (int*)p;     p += Ep * 4;
    int*    ebuf      = (int*)p;     p += Ep * 4;
    int*    btot      = (int*)p;     p += NBp * 4;
    int*    bbase     = (int*)p;     p += (NBp + 16) * 4;
    int*    bcur      = (int*)p;     p += NBp * 4;

    int nblkE = (E + CHUNK - 1) / CHUNK;

    hipMemsetAsync(btot, 0, NBp * sizeof(int), stream);
    bucket_hist<<<nblkE + 1, BINTHREADS, 0, stream>>>(col, btot, E, NB, W1, W1t, nblkE);
    bucket_scan<<<1, 256, 0, stream>>>(btot, bbase, bcur, row_start, NB, N, E);
    phaseA<<<nblkE, BINTHREADS, 0, stream>>>(row, col, bcur, ebuf, E, NB);
    phaseB<<<NB, 256, 0, stream>>>(ebuf, bbase, row_start, csr_row, dinv, N);
    gemm1<<<(N + 31) / 32, 256, 0, stream>>>(x, W1t, dinv, hs1, N);
    agg_l1<<<(N + 31) / 32, 256, 0, stream>>>(hs1, row_start, csr_row, dinv, b1, W2, h2s, N);
    agg2_final<<<(N + 31) / 32, 256, 0, stream>>>(h2s, row_start, csr_row, dinv, b2, out, N);
}